// Round 1
// baseline (1497.924 us; speedup 1.0000x reference)
//
#include <hip/hip_runtime.h>
#include <math.h>

#define B_ 16384
#define R_ 512
#define V_ 1000
#define F_ 300
#define L_ 512
#define H_ 512
#define LEAK_ 0.2f
#define TEMP_ 0.07f
#define DISK_ 15

__device__ __forceinline__ float waveReduceSum(float v) {
#pragma unroll
    for (int off = 32; off; off >>= 1) v += __shfl_xor(v, off);
    return v;
}

// ---------------------------------------------------------------------------
// init: zero loss accumulators + z_rel row 0
// ---------------------------------------------------------------------------
__global__ void init_kernel(float* __restrict__ out) {
    int i = blockIdx.x * blockDim.x + threadIdx.x;
    if (i < 2 + L_) out[i] = 0.f;
}

// ---------------------------------------------------------------------------
// top-2 / bottom-15 per row. one wave per row.
// ---------------------------------------------------------------------------
__global__ __launch_bounds__(64) void topk_kernel(
    const float* __restrict__ logits, int* __restrict__ top0,
    int* __restrict__ top1, int* __restrict__ dis) {
    int b = blockIdx.x;
    int lane = threadIdx.x;
    const float* lp = logits + (size_t)b * R_;
    float v[8];
#pragma unroll
    for (int i = 0; i < 8; ++i) v[i] = lp[i * 64 + lane];

    int t0 = 0, t1 = 0;
#pragma unroll
    for (int pass = 0; pass < 2; ++pass) {
        float bv = -INFINITY; int bi = R_;
#pragma unroll
        for (int i = 0; i < 8; ++i) {
            int idx = i * 64 + lane;
            if (v[i] > bv || (v[i] == bv && idx < bi)) { bv = v[i]; bi = idx; }
        }
#pragma unroll
        for (int off = 32; off; off >>= 1) {
            float ov = __shfl_xor(bv, off);
            int   oi = __shfl_xor(bi, off);
            if (ov > bv || (ov == bv && oi < bi)) { bv = ov; bi = oi; }
        }
        if (pass == 0) t0 = bi; else t1 = bi;
        if ((bi & 63) == lane) v[bi >> 6] = -INFINITY;  // remove for 2nd max
    }
    // removed maxima must not appear in bottom-15: mark +inf
    if ((t0 & 63) == lane) v[t0 >> 6] = INFINITY;
    if ((t1 & 63) == lane) v[t1 >> 6] = INFINITY;

    int dloc[DISK_];
#pragma unroll
    for (int t = 0; t < DISK_; ++t) {
        float bv = INFINITY; int bi = R_;
#pragma unroll
        for (int i = 0; i < 8; ++i) {
            int idx = i * 64 + lane;
            if (v[i] < bv || (v[i] == bv && idx < bi)) { bv = v[i]; bi = idx; }
        }
#pragma unroll
        for (int off = 32; off; off >>= 1) {
            float ov = __shfl_xor(bv, off);
            int   oi = __shfl_xor(bi, off);
            if (ov < bv || (ov == bv && oi < bi)) { bv = ov; bi = oi; }
        }
        dloc[t] = bi;
        if ((bi & 63) == lane) v[bi >> 6] = INFINITY;
    }
    if (lane == 0) {
        top0[b] = t0; top1[b] = t1;
#pragma unroll
        for (int t = 0; t < DISK_; ++t) dis[b * DISK_ + t] = dloc[t];
    }
}

// ---------------------------------------------------------------------------
// per-relation tables: d[r], P1=d@W1a, P2=d@W1b, P3=d@W3b, ipost=mlp2(d)
// 4 relations per block, 128 blocks.
// ---------------------------------------------------------------------------
#define RPB 4
__global__ __launch_bounds__(256) void tables_kernel(
    const int* __restrict__ rels32, const float* __restrict__ rel_dict,
    const float* __restrict__ W1, const float* __restrict__ W3,
    const float* __restrict__ iW1, const float* __restrict__ ib1,
    const float* __restrict__ iW2, const float* __restrict__ ib2,
    float* __restrict__ d_table, float* __restrict__ P1,
    float* __restrict__ P2, float* __restrict__ P3,
    float* __restrict__ ipost) {
    __shared__ float dl[RPB][F_];
    __shared__ float hl[RPB][H_];
    __shared__ int s_i64;
    int tid = threadIdx.x;
    int r0 = blockIdx.x * RPB;

    if (tid == 0) s_i64 = 1;
    __syncthreads();
    // int64-layout detection: odd int32 words are high halves (all zero) iff int64
    if (rels32[2 * tid + 1] != 0) s_i64 = 0;
    __syncthreads();
    int i64 = s_i64;

    for (int e = tid; e < RPB * F_; e += 256) {
        int r = e / F_, k = e - r * F_;
        int rr = r0 + r;
        int key = i64 ? rels32[4 * rr + 2] : rels32[2 * rr + 1];
        float val = rel_dict[key * F_ + k];
        dl[r][k] = val;
        d_table[rr * F_ + k] = val;
    }
    __syncthreads();

    for (int j = tid; j < H_; j += 256) {
        float a1[RPB] = {}, a2[RPB] = {}, a3[RPB] = {}, ai[RPB] = {};
        for (int k = 0; k < F_; ++k) {
            float w1a = W1[k * H_ + j];
            float w1b = W1[(F_ + k) * H_ + j];
            float w3  = W3[(L_ + k) * H_ + j];
            float wi  = iW1[k * H_ + j];
#pragma unroll
            for (int r = 0; r < RPB; ++r) {
                float dv = dl[r][k];
                a1[r] += dv * w1a; a2[r] += dv * w1b;
                a3[r] += dv * w3;  ai[r] += dv * wi;
            }
        }
#pragma unroll
        for (int r = 0; r < RPB; ++r) {
            P1[(r0 + r) * H_ + j] = a1[r];
            P2[(r0 + r) * H_ + j] = a2[r];
            P3[(r0 + r) * H_ + j] = a3[r];
            float h = ai[r] + ib1[j];
            hl[r][j] = h > 0.f ? h : 0.f;
        }
    }
    __syncthreads();

    for (int j = tid; j < H_; j += 256) {
        float acc[RPB] = {};
        for (int k = 0; k < H_; ++k) {
            float w = iW2[k * H_ + j];
#pragma unroll
            for (int r = 0; r < RPB; ++r) acc[r] += hl[r][k] * w;
        }
#pragma unroll
        for (int r = 0; r < RPB; ++r) {
            float vv = acc[r] + ib2[j];
            ipost[(r0 + r) * H_ + j] = vv > 0.f ? vv : 0.f;
        }
    }
}

// ---------------------------------------------------------------------------
// h1 = leaky(P1[top0] + P2[top1] + b1)
// ---------------------------------------------------------------------------
__global__ __launch_bounds__(256) void h1_kernel(
    const float* __restrict__ P1, const float* __restrict__ P2,
    const float* __restrict__ b1, const int* __restrict__ top0,
    const int* __restrict__ top1, float* __restrict__ h1) {
    int idx = blockIdx.x * 256 + threadIdx.x;
    int b = idx >> 9, j = idx & 511;
    float v = P1[top0[b] * H_ + j] + P2[top1[b] * H_ + j] + b1[j];
    h1[idx] = v > 0.f ? v : LEAK_ * v;
}

// ---------------------------------------------------------------------------
// z = mu + eps1*exp(ls) (in place over mu); z_ = mu + eps2*exp(ls) (over ls);
// kl partial sums -> atomic
// ---------------------------------------------------------------------------
__global__ __launch_bounds__(256) void zkl_kernel(
    float* __restrict__ mu_z, float* __restrict__ ls_z,
    const float* __restrict__ eps1, const float* __restrict__ eps2,
    float* __restrict__ loss0) {
    int idx = blockIdx.x * 256 + threadIdx.x;
    int stride = gridDim.x * 256;
    float kl = 0.f;
    for (int i = idx; i < B_ * L_; i += stride) {
        float m = mu_z[i], l = ls_z[i];
        float s = __expf(l);
        mu_z[i] = m + eps1[i] * s;
        ls_z[i] = m + eps2[i] * s;
        kl += -0.5f * (1.f + 2.f * l - m * m - s * s);
    }
    __shared__ float red[4];
    kl = waveReduceSum(kl);
    int lane = threadIdx.x & 63, w = threadIdx.x >> 6;
    if (lane == 0) red[w] = kl;
    __syncthreads();
    if (threadIdx.x == 0) atomicAdd(loss0, red[0] + red[1] + red[2] + red[3]);
}

// ---------------------------------------------------------------------------
// fp32 GEMM: C[M,N] = A[M,512] @ W[512,N], 64x64 tile, 1 wave, 8x8 microtile,
// double-buffered LDS, register-prefetched globals. Fused epilogues:
//  EPI 0: C = acc + bias
//  EPI 1: C = leaky(acc + bias + table[rowsel[row]*tld + col])      (h3)
//  EPI 2: C = relu(acc + bias)                                     (t, z_p)
//  EPI 3: loss += sum (tanh(acc+bias) - table[rowsel[row]*tld+col])^2 (recon)
// ---------------------------------------------------------------------------
#define GKT 16
template <int EPI>
__global__ __launch_bounds__(64) void gemm64(
    const float* __restrict__ A, const float* __restrict__ W,
    float* __restrict__ C, int N, int ldc,
    const float* __restrict__ bias,
    const float* __restrict__ table, int tld,
    const int* __restrict__ rowsel, float* __restrict__ lossp) {
    __shared__ float As[2][GKT][68];
    __shared__ float Bs[2][GKT][64];
    const int K = 512;
    int lane = threadIdx.x;
    int tx = lane & 7, ty = lane >> 3;
    int row0 = blockIdx.y * 64, col0 = blockIdx.x * 64;

    float acc[8][8] = {};
    float4 aReg[4], bReg[4];

    auto loadA = [&](int k0) {
#pragma unroll
        for (int it = 0; it < 4; ++it) {
            int row = row0 + it * 16 + (lane >> 2);
            int kf = (lane & 3) * 4;
            aReg[it] = *(const float4*)&A[(size_t)row * K + k0 + kf];
        }
    };
    auto loadB = [&](int k0) {
#pragma unroll
        for (int it = 0; it < 4; ++it) {
            int kk = it * 4 + (lane >> 4);
            int col = col0 + (lane & 15) * 4;
            if (col + 3 < N) {
                bReg[it] = *(const float4*)&W[(size_t)(k0 + kk) * N + col];
            } else {
                float4 t;
                t.x = (col + 0 < N) ? W[(size_t)(k0 + kk) * N + col + 0] : 0.f;
                t.y = (col + 1 < N) ? W[(size_t)(k0 + kk) * N + col + 1] : 0.f;
                t.z = (col + 2 < N) ? W[(size_t)(k0 + kk) * N + col + 2] : 0.f;
                t.w = (col + 3 < N) ? W[(size_t)(k0 + kk) * N + col + 3] : 0.f;
                bReg[it] = t;
            }
        }
    };
    auto storeA = [&](int p) {
#pragma unroll
        for (int it = 0; it < 4; ++it) {
            int m = it * 16 + (lane >> 2);
            int kf = (lane & 3) * 4;
            As[p][kf + 0][m] = aReg[it].x;
            As[p][kf + 1][m] = aReg[it].y;
            As[p][kf + 2][m] = aReg[it].z;
            As[p][kf + 3][m] = aReg[it].w;
        }
    };
    auto storeB = [&](int p) {
#pragma unroll
        for (int it = 0; it < 4; ++it) {
            int kk = it * 4 + (lane >> 4);
            int cf = (lane & 15) * 4;
            *(float4*)&Bs[p][kk][cf] = bReg[it];
        }
    };

    int p = 0;
    loadA(0); loadB(0);
    storeA(p); storeB(p);
    for (int k0 = 0; k0 < K; k0 += GKT) {
        __syncthreads();
        bool more = (k0 + GKT) < K;
        if (more) { loadA(k0 + GKT); loadB(k0 + GKT); }
#pragma unroll
        for (int kk = 0; kk < GKT; ++kk) {
            float a[8], b[8];
            *(float4*)&a[0] = *(const float4*)&As[p][kk][ty * 8];
            *(float4*)&a[4] = *(const float4*)&As[p][kk][ty * 8 + 4];
            *(float4*)&b[0] = *(const float4*)&Bs[p][kk][tx * 8];
            *(float4*)&b[4] = *(const float4*)&Bs[p][kk][tx * 8 + 4];
#pragma unroll
            for (int i = 0; i < 8; ++i)
#pragma unroll
                for (int j = 0; j < 8; ++j) acc[i][j] += a[i] * b[j];
        }
        p ^= 1;
        if (more) { storeA(p); storeB(p); }
    }

    int rbase = row0 + ty * 8;
    int cbase = col0 + tx * 8;
    if (EPI == 3) {
        float lsum = 0.f;
#pragma unroll
        for (int i = 0; i < 8; ++i) {
            int row = rbase + i;
            const float* tr = table + (size_t)rowsel[row] * tld;
#pragma unroll
            for (int j = 0; j < 8; ++j) {
                int col = cbase + j;
                if (col < N) {
                    float v = tanhf(acc[i][j] + bias[col]);
                    float d = v - tr[col];
                    lsum += d * d;
                }
            }
        }
        lsum = waveReduceSum(lsum);
        if (lane == 0) atomicAdd(lossp, lsum);
    } else {
#pragma unroll
        for (int i = 0; i < 8; ++i) {
            int row = rbase + i;
            const float* tr = (EPI == 1) ? table + (size_t)rowsel[row] * tld : nullptr;
#pragma unroll
            for (int j = 0; j < 8; ++j) {
                int col = cbase + j;
                float v = acc[i][j] + bias[col];
                if (EPI == 1) { v += tr[col]; v = v > 0.f ? v : LEAK_ * v; }
                if (EPI == 2) { v = v > 0.f ? v : 0.f; }
                C[(size_t)row * ldc + col] = v;
            }
        }
    }
}

// ---------------------------------------------------------------------------
// contrastive loss: one wave per row
// ---------------------------------------------------------------------------
__global__ __launch_bounds__(256) void csl_kernel(
    const float* __restrict__ zp, const float* __restrict__ ipost,
    const int* __restrict__ top0, const int* __restrict__ dis,
    float* __restrict__ loss1) {
    int w = threadIdx.x >> 6, lane = threadIdx.x & 63;
    int b = blockIdx.x * 4 + w;
    const float* zr = zp + (size_t)b * 512;
    float z[8];
#pragma unroll
    for (int i = 0; i < 8; ++i) z[i] = zr[i * 64 + lane];
    int cand[16];
    cand[0] = top0[b];
#pragma unroll
    for (int n = 0; n < DISK_; ++n) cand[n + 1] = dis[b * DISK_ + n];
    float s[16];
#pragma unroll
    for (int c = 0; c < 16; ++c) {
        const float* ip = ipost + (size_t)cand[c] * 512;
        float a = 0.f;
#pragma unroll
        for (int i = 0; i < 8; ++i) a += z[i] * ip[i * 64 + lane];
        s[c] = waveReduceSum(a);
    }
    if (lane == 0) {
        float m = s[0];
#pragma unroll
        for (int c = 1; c < 16; ++c) m = fmaxf(m, s[c]);
        float se = 0.f;
#pragma unroll
        for (int c = 0; c < 16; ++c) se += __expf((s[c] - m) / TEMP_);
        float loss = -((s[0] - m) / TEMP_ - __logf(se));
        atomicAdd(loss1, loss);
    }
}

// ---------------------------------------------------------------------------
extern "C" void kernel_launch(void* const* d_in, const int* in_sizes, int n_in,
                              void* d_out, int out_size, void* d_ws, size_t ws_size,
                              hipStream_t stream) {
    const float* logits  = (const float*)d_in[0];
    const int*   rels    = (const int*)d_in[1];
    const float* rel_dict= (const float*)d_in[2];
    const float* eps1    = (const float*)d_in[3];
    const float* eps2    = (const float*)d_in[4];
    const float* W1  = (const float*)d_in[5];
    const float* b1  = (const float*)d_in[6];
    const float* Wmu = (const float*)d_in[7];
    const float* bmu = (const float*)d_in[8];
    const float* Wls = (const float*)d_in[9];
    const float* bls = (const float*)d_in[10];
    const float* W3  = (const float*)d_in[11];
    const float* b3  = (const float*)d_in[12];
    const float* W4  = (const float*)d_in[13];
    const float* b4  = (const float*)d_in[14];
    const float* iW1 = (const float*)d_in[15];
    const float* ib1 = (const float*)d_in[16];
    const float* iW2 = (const float*)d_in[17];
    const float* ib2 = (const float*)d_in[18];
    const float* zW1 = (const float*)d_in[19];
    const float* zb1 = (const float*)d_in[20];
    const float* zW2 = (const float*)d_in[21];
    const float* zb2 = (const float*)d_in[22];
    float* out = (float*)d_out;

    char* w = (char*)d_ws;
    size_t off = 0;
    auto alloc = [&](size_t bytes) { void* p = w + off; off += (bytes + 255) & ~(size_t)255; return p; };
    int*   top0    = (int*)alloc(B_ * 4);
    int*   top1    = (int*)alloc(B_ * 4);
    int*   dis     = (int*)alloc(B_ * DISK_ * 4);
    float* d_table = (float*)alloc((size_t)R_ * F_ * 4);
    float* P1      = (float*)alloc((size_t)R_ * H_ * 4);
    float* P2      = (float*)alloc((size_t)R_ * H_ * 4);
    float* P3      = (float*)alloc((size_t)R_ * H_ * 4);
    float* ipost   = (float*)alloc((size_t)R_ * H_ * 4);
    float* buf0    = (float*)alloc((size_t)B_ * H_ * 4);  // h1 -> h3
    float* buf1    = (float*)alloc((size_t)B_ * H_ * 4);  // mu -> z -> t
    float* buf2    = (float*)alloc((size_t)B_ * H_ * 4);  // ls -> z_

    init_kernel<<<3, 256, 0, stream>>>(out);
    topk_kernel<<<B_, 64, 0, stream>>>(logits, top0, top1, dis);
    tables_kernel<<<R_ / RPB, 256, 0, stream>>>(rels, rel_dict, W1, W3, iW1, ib1,
                                                iW2, ib2, d_table, P1, P2, P3, ipost);
    h1_kernel<<<B_ * H_ / 256, 256, 0, stream>>>(P1, P2, b1, top0, top1, buf0);

    dim3 g8(8, 256), g5(5, 256);
    // mu, ls
    gemm64<0><<<g8, 64, 0, stream>>>(buf0, Wmu, buf1, 512, 512, bmu, nullptr, 0, nullptr, nullptr);
    gemm64<0><<<g8, 64, 0, stream>>>(buf0, Wls, buf2, 512, 512, bls, nullptr, 0, nullptr, nullptr);
    // z / z_ / kl
    zkl_kernel<<<2048, 256, 0, stream>>>(buf1, buf2, eps1, eps2, out);
    // h3 = leaky(z @ W3[:512] + P3[top1] + b3)
    gemm64<1><<<g8, 64, 0, stream>>>(buf1, W3, buf0, 512, 512, b3, P3, H_, top1, nullptr);
    // recon loss
    gemm64<3><<<g5, 64, 0, stream>>>(buf0, W4, nullptr, 300, 0, b4, d_table, F_, top0, out);
    // t = relu(z_ @ zW1 + zb1)
    gemm64<2><<<g8, 64, 0, stream>>>(buf2, zW1, buf1, 512, 512, zb1, nullptr, 0, nullptr, nullptr);
    // z_p = relu(t @ zW2 + zb2) -> z_rel rows 1..B
    gemm64<2><<<g8, 64, 0, stream>>>(buf1, zW2, out + 2 + L_, 512, 512, zb2, nullptr, 0, nullptr, nullptr);
    // contrastive loss
    csl_kernel<<<B_ / 4, 256, 0, stream>>>(out + 2 + L_, ipost, top0, dis, out + 1);
}

// Round 2
// 959.494 us; speedup vs baseline: 1.5612x; 1.5612x over previous
//
#include <hip/hip_runtime.h>
#include <math.h>

#define B_ 16384
#define R_ 512
#define V_ 1000
#define F_ 300
#define L_ 512
#define H_ 512
#define LEAK_ 0.2f
#define TEMP_ 0.07f
#define DISK_ 15

typedef short short8 __attribute__((ext_vector_type(8)));
typedef float float4v __attribute__((ext_vector_type(4)));

__device__ __forceinline__ float waveReduceSum(float v) {
#pragma unroll
    for (int off = 32; off; off >>= 1) v += __shfl_xor(v, off);
    return v;
}

__device__ __forceinline__ short f2bf(float f) {
    unsigned u = __float_as_uint(f);
    unsigned r = (u + 0x7FFFu + ((u >> 16) & 1u)) >> 16;
    return (short)r;
}

// ---------------------------------------------------------------------------
// init: zero loss accumulators + z_rel row 0
// ---------------------------------------------------------------------------
__global__ void init_kernel(float* __restrict__ out) {
    int i = blockIdx.x * blockDim.x + threadIdx.x;
    if (i < 2 + L_) out[i] = 0.f;
}

// ---------------------------------------------------------------------------
// top-2 / bottom-15 per row. one wave per row.
// ---------------------------------------------------------------------------
__global__ __launch_bounds__(64) void topk_kernel(
    const float* __restrict__ logits, int* __restrict__ top0,
    int* __restrict__ top1, int* __restrict__ dis) {
    int b = blockIdx.x;
    int lane = threadIdx.x;
    const float* lp = logits + (size_t)b * R_;
    float v[8];
#pragma unroll
    for (int i = 0; i < 8; ++i) v[i] = lp[i * 64 + lane];

    int t0 = 0, t1 = 0;
#pragma unroll
    for (int pass = 0; pass < 2; ++pass) {
        float bv = -INFINITY; int bi = R_;
#pragma unroll
        for (int i = 0; i < 8; ++i) {
            int idx = i * 64 + lane;
            if (v[i] > bv || (v[i] == bv && idx < bi)) { bv = v[i]; bi = idx; }
        }
#pragma unroll
        for (int off = 32; off; off >>= 1) {
            float ov = __shfl_xor(bv, off);
            int   oi = __shfl_xor(bi, off);
            if (ov > bv || (ov == bv && oi < bi)) { bv = ov; bi = oi; }
        }
        if (pass == 0) t0 = bi; else t1 = bi;
        if ((bi & 63) == lane) v[bi >> 6] = -INFINITY;
    }
    if ((t0 & 63) == lane) v[t0 >> 6] = INFINITY;
    if ((t1 & 63) == lane) v[t1 >> 6] = INFINITY;

    int dloc[DISK_];
#pragma unroll
    for (int t = 0; t < DISK_; ++t) {
        float bv = INFINITY; int bi = R_;
#pragma unroll
        for (int i = 0; i < 8; ++i) {
            int idx = i * 64 + lane;
            if (v[i] < bv || (v[i] == bv && idx < bi)) { bv = v[i]; bi = idx; }
        }
#pragma unroll
        for (int off = 32; off; off >>= 1) {
            float ov = __shfl_xor(bv, off);
            int   oi = __shfl_xor(bi, off);
            if (ov < bv || (ov == bv && oi < bi)) { bv = ov; bi = oi; }
        }
        dloc[t] = bi;
        if ((bi & 63) == lane) v[bi >> 6] = INFINITY;
    }
    if (lane == 0) {
        top0[b] = t0; top1[b] = t1;
#pragma unroll
        for (int t = 0; t < DISK_; ++t) dis[b * DISK_ + t] = dloc[t];
    }
}

// ---------------------------------------------------------------------------
// per-relation tables: d[r], P1=d@W1a, P2=d@W1b, P3=d@W3b, ipost=mlp2(d)
// ---------------------------------------------------------------------------
#define RPB 4
__global__ __launch_bounds__(256) void tables_kernel(
    const int* __restrict__ rels32, const float* __restrict__ rel_dict,
    const float* __restrict__ W1, const float* __restrict__ W3,
    const float* __restrict__ iW1, const float* __restrict__ ib1,
    const float* __restrict__ iW2, const float* __restrict__ ib2,
    float* __restrict__ d_table, float* __restrict__ P1,
    float* __restrict__ P2, float* __restrict__ P3,
    float* __restrict__ ipost) {
    __shared__ float dl[RPB][F_];
    __shared__ float hl[RPB][H_];
    __shared__ int s_i64;
    int tid = threadIdx.x;
    int r0 = blockIdx.x * RPB;

    if (tid == 0) s_i64 = 1;
    __syncthreads();
    if (rels32[2 * tid + 1] != 0) s_i64 = 0;
    __syncthreads();
    int i64 = s_i64;

    for (int e = tid; e < RPB * F_; e += 256) {
        int r = e / F_, k = e - r * F_;
        int rr = r0 + r;
        int key = i64 ? rels32[4 * rr + 2] : rels32[2 * rr + 1];
        float val = rel_dict[key * F_ + k];
        dl[r][k] = val;
        d_table[rr * F_ + k] = val;
    }
    __syncthreads();

    for (int j = tid; j < H_; j += 256) {
        float a1[RPB] = {}, a2[RPB] = {}, a3[RPB] = {}, ai[RPB] = {};
        for (int k = 0; k < F_; ++k) {
            float w1a = W1[k * H_ + j];
            float w1b = W1[(F_ + k) * H_ + j];
            float w3  = W3[(L_ + k) * H_ + j];
            float wi  = iW1[k * H_ + j];
#pragma unroll
            for (int r = 0; r < RPB; ++r) {
                float dv = dl[r][k];
                a1[r] += dv * w1a; a2[r] += dv * w1b;
                a3[r] += dv * w3;  ai[r] += dv * wi;
            }
        }
#pragma unroll
        for (int r = 0; r < RPB; ++r) {
            P1[(r0 + r) * H_ + j] = a1[r];
            P2[(r0 + r) * H_ + j] = a2[r];
            P3[(r0 + r) * H_ + j] = a3[r];
            float h = ai[r] + ib1[j];
            hl[r][j] = h > 0.f ? h : 0.f;
        }
    }
    __syncthreads();

    for (int j = tid; j < H_; j += 256) {
        float acc[RPB] = {};
        for (int k = 0; k < H_; ++k) {
            float w = iW2[k * H_ + j];
#pragma unroll
            for (int r = 0; r < RPB; ++r) acc[r] += hl[r][k] * w;
        }
#pragma unroll
        for (int r = 0; r < RPB; ++r) {
            float vv = acc[r] + ib2[j];
            ipost[(r0 + r) * H_ + j] = vv > 0.f ? vv : 0.f;
        }
    }
}

// ---------------------------------------------------------------------------
// transpose fp32 W[K][N] -> bf16 Wt[Npad][K]  (rows >= N zero-filled)
// ---------------------------------------------------------------------------
__global__ __launch_bounds__(256) void transpose_w(
    const float* __restrict__ W, short* __restrict__ Wt, int K, int N, int Npad) {
    __shared__ float tile[32][33];
    int tx = threadIdx.x & 31, ty = threadIdx.x >> 5;
    int k0 = blockIdx.x * 32, n0 = blockIdx.y * 32;
#pragma unroll
    for (int i = 0; i < 4; ++i) {
        int k = k0 + i * 8 + ty, n = n0 + tx;
        tile[i * 8 + ty][tx] = (n < N) ? W[(size_t)k * N + n] : 0.f;
    }
    __syncthreads();
#pragma unroll
    for (int i = 0; i < 4; ++i) {
        int n = n0 + i * 8 + ty, k = k0 + tx;
        if (n < Npad) Wt[(size_t)n * K + k] = f2bf(tile[tx][i * 8 + ty]);
    }
}

// ---------------------------------------------------------------------------
// h1 = leaky(P1[top0] + P2[top1] + b1)  -> bf16
// ---------------------------------------------------------------------------
__global__ __launch_bounds__(256) void h1_kernel(
    const float* __restrict__ P1, const float* __restrict__ P2,
    const float* __restrict__ b1, const int* __restrict__ top0,
    const int* __restrict__ top1, short* __restrict__ h1b) {
    int idx = blockIdx.x * 256 + threadIdx.x;
    int b = idx >> 9, j = idx & 511;
    float v = P1[top0[b] * H_ + j] + P2[top1[b] * H_ + j] + b1[j];
    h1b[idx] = f2bf(v > 0.f ? v : LEAK_ * v);
}

// ---------------------------------------------------------------------------
// z / z_ (bf16) + kl loss from fp32 mu/ls
// ---------------------------------------------------------------------------
__global__ __launch_bounds__(256) void zkl_kernel(
    const float* __restrict__ mu, const float* __restrict__ ls,
    const float* __restrict__ eps1, const float* __restrict__ eps2,
    short* __restrict__ zb, short* __restrict__ z_b, float* __restrict__ loss0) {
    int idx = blockIdx.x * 256 + threadIdx.x;
    int stride = gridDim.x * 256;
    float kl = 0.f;
    for (int i = idx; i < B_ * L_; i += stride) {
        float m = mu[i], l = ls[i];
        float s = __expf(l);
        zb[i]  = f2bf(m + eps1[i] * s);
        z_b[i] = f2bf(m + eps2[i] * s);
        kl += -0.5f * (1.f + 2.f * l - m * m - s * s);
    }
    __shared__ float red[4];
    kl = waveReduceSum(kl);
    int lane = threadIdx.x & 63, w = threadIdx.x >> 6;
    if (lane == 0) red[w] = kl;
    __syncthreads();
    if (threadIdx.x == 0) atomicAdd(loss0, red[0] + red[1] + red[2] + red[3]);
}

// ---------------------------------------------------------------------------
// bf16 MFMA GEMM: C[M,*] = A[M,512](bf16) @ Wt[N,512](bf16, pre-transposed)
// block: 256 thr (4 waves), tile 128(M) x 64(N), BK=32, double-buffered LDS.
// wave w: rows [w*32, w*32+32), all 64 cols; 2x4 grid of 16x16x32 MFMAs.
//  EPI 0: fp32 store  acc + bias                       (mu, ls)
//  EPI 1: bf16 store  leaky(acc + bias + P3[rowsel])   (h3)
//  EPI 2: bf16 store  relu(acc + bias)                 (t)
//  EPI 3: loss += (tanh(acc+bias) - table[rowsel])^2   (recon)
//  EPI 4: fp32 store  relu(acc + bias)                 (z_p)
// ---------------------------------------------------------------------------
template <int EPI>
__global__ __launch_bounds__(256) void gemm_mfma(
    const short* __restrict__ A, const short* __restrict__ Wt,
    void* __restrict__ C, const float* __restrict__ bias,
    const float* __restrict__ table, int tld,
    const int* __restrict__ rowsel, float* __restrict__ lossp, int N) {
    __shared__ __align__(16) short Asl[2][128][40];
    __shared__ __align__(16) short Bsl[2][64][40];
    const int K = 512;
    int tid = threadIdx.x;
    int lane = tid & 63, wv = tid >> 6;
    int lm = lane & 15, q = lane >> 4;
    int row0 = blockIdx.y * 128;
    int col0 = blockIdx.x * 64;

    float4v acc[2][4];
#pragma unroll
    for (int i = 0; i < 2; ++i)
#pragma unroll
        for (int j = 0; j < 4; ++j) acc[i][j] = {0.f, 0.f, 0.f, 0.f};

    uint4 aReg[2], bReg;
    // A chunks: 512 chunks of 16B (128 rows x 4), threads t and t+256
    int ar0 = tid >> 2, ak = (tid & 3) * 8;           // chunk tid
    int ar1 = (tid + 256) >> 2;                       // chunk tid+256 (same ak)
    // B chunks: 256 chunks (64 rows x 4)
    int br = tid >> 2, bk = (tid & 3) * 8;

    auto loadG = [&](int k0) {
        aReg[0] = *(const uint4*)&A[(size_t)(row0 + ar0) * K + k0 + ak];
        aReg[1] = *(const uint4*)&A[(size_t)(row0 + ar1) * K + k0 + ak];
        bReg    = *(const uint4*)&Wt[(size_t)(col0 + br) * K + k0 + bk];
    };
    auto storeL = [&](int p) {
        *(uint4*)&Asl[p][ar0][ak] = aReg[0];
        *(uint4*)&Asl[p][ar1][ak] = aReg[1];
        *(uint4*)&Bsl[p][br][bk]  = bReg;
    };

    int p = 0;
    loadG(0);
    storeL(0);
    for (int k0 = 0; k0 < K; k0 += 32) {
        __syncthreads();
        bool more = (k0 + 32) < K;
        if (more) loadG(k0 + 32);
        short8 af[2], bfr[4];
#pragma unroll
        for (int mt = 0; mt < 2; ++mt)
            af[mt] = *(const short8*)&Asl[p][wv * 32 + mt * 16 + lm][q * 8];
#pragma unroll
        for (int nt = 0; nt < 4; ++nt)
            bfr[nt] = *(const short8*)&Bsl[p][nt * 16 + lm][q * 8];
#pragma unroll
        for (int mt = 0; mt < 2; ++mt)
#pragma unroll
            for (int nt = 0; nt < 4; ++nt)
                acc[mt][nt] = __builtin_amdgcn_mfma_f32_16x16x32_bf16(
                    af[mt], bfr[nt], acc[mt][nt], 0, 0, 0);
        if (more) { p ^= 1; storeL(p); }
    }

    if (EPI == 3) {
        float lsum = 0.f;
#pragma unroll
        for (int mt = 0; mt < 2; ++mt) {
#pragma unroll
            for (int r = 0; r < 4; ++r) {
                int grow = row0 + wv * 32 + mt * 16 + q * 4 + r;
                int trow = rowsel[grow];
#pragma unroll
                for (int nt = 0; nt < 4; ++nt) {
                    int gcol = col0 + nt * 16 + lm;
                    if (gcol < N) {
                        float v = tanhf(acc[mt][nt][r] + bias[gcol]);
                        float d = v - table[(size_t)trow * tld + gcol];
                        lsum += d * d;
                    }
                }
            }
        }
        lsum = waveReduceSum(lsum);
        if (lane == 0) atomicAdd(lossp, lsum);
    } else {
#pragma unroll
        for (int mt = 0; mt < 2; ++mt) {
#pragma unroll
            for (int r = 0; r < 4; ++r) {
                int grow = row0 + wv * 32 + mt * 16 + q * 4 + r;
                int trow = (EPI == 1) ? rowsel[grow] : 0;
#pragma unroll
                for (int nt = 0; nt < 4; ++nt) {
                    int gcol = col0 + nt * 16 + lm;
                    float v = acc[mt][nt][r] + bias[gcol];
                    if (EPI == 1) {
                        v += table[(size_t)trow * tld + gcol];
                        v = v > 0.f ? v : LEAK_ * v;
                    }
                    if (EPI == 2 || EPI == 4) v = v > 0.f ? v : 0.f;
                    if (EPI == 0 || EPI == 4)
                        ((float*)C)[(size_t)grow * 512 + gcol] = v;
                    else
                        ((short*)C)[(size_t)grow * 512 + gcol] = f2bf(v);
                }
            }
        }
    }
}

// ---------------------------------------------------------------------------
// contrastive loss: one wave per row, interleaved butterfly reduction
// ---------------------------------------------------------------------------
__global__ __launch_bounds__(256) void csl_kernel(
    const float* __restrict__ zp, const float* __restrict__ ipost,
    const int* __restrict__ top0, const int* __restrict__ dis,
    float* __restrict__ loss1) {
    int w = threadIdx.x >> 6, lane = threadIdx.x & 63;
    int b = blockIdx.x * 4 + w;
    const float* zr = zp + (size_t)b * 512;
    float z[8];
#pragma unroll
    for (int i = 0; i < 8; ++i) z[i] = zr[i * 64 + lane];
    int cand[16];
    cand[0] = top0[b];
#pragma unroll
    for (int n = 0; n < DISK_; ++n) cand[n + 1] = dis[b * DISK_ + n];
    float s[16];
#pragma unroll
    for (int c = 0; c < 16; ++c) {
        const float* ip = ipost + (size_t)cand[c] * 512;
        float a = 0.f;
#pragma unroll
        for (int i = 0; i < 8; ++i) a += z[i] * ip[i * 64 + lane];
        s[c] = a;
    }
    // interleaved butterfly: 6 rounds x 16 independent shuffles
#pragma unroll
    for (int off = 32; off; off >>= 1) {
        float o[16];
#pragma unroll
        for (int c = 0; c < 16; ++c) o[c] = __shfl_xor(s[c], off);
#pragma unroll
        for (int c = 0; c < 16; ++c) s[c] += o[c];
    }
    if (lane == 0) {
        float m = s[0];
#pragma unroll
        for (int c = 1; c < 16; ++c) m = fmaxf(m, s[c]);
        float se = 0.f;
#pragma unroll
        for (int c = 0; c < 16; ++c) se += __expf((s[c] - m) / TEMP_);
        float loss = -((s[0] - m) / TEMP_ - __logf(se));
        atomicAdd(loss1, loss);
    }
}

// ---------------------------------------------------------------------------
extern "C" void kernel_launch(void* const* d_in, const int* in_sizes, int n_in,
                              void* d_out, int out_size, void* d_ws, size_t ws_size,
                              hipStream_t stream) {
    const float* logits  = (const float*)d_in[0];
    const int*   rels    = (const int*)d_in[1];
    const float* rel_dict= (const float*)d_in[2];
    const float* eps1    = (const float*)d_in[3];
    const float* eps2    = (const float*)d_in[4];
    const float* W1  = (const float*)d_in[5];
    const float* b1  = (const float*)d_in[6];
    const float* Wmu = (const float*)d_in[7];
    const float* bmu = (const float*)d_in[8];
    const float* Wls = (const float*)d_in[9];
    const float* bls = (const float*)d_in[10];
    const float* W3  = (const float*)d_in[11];
    const float* b3  = (const float*)d_in[12];
    const float* W4  = (const float*)d_in[13];
    const float* b4  = (const float*)d_in[14];
    const float* iW1 = (const float*)d_in[15];
    const float* ib1 = (const float*)d_in[16];
    const float* iW2 = (const float*)d_in[17];
    const float* ib2 = (const float*)d_in[18];
    const float* zW1 = (const float*)d_in[19];
    const float* zb1 = (const float*)d_in[20];
    const float* zW2 = (const float*)d_in[21];
    const float* zb2 = (const float*)d_in[22];
    float* out = (float*)d_out;

    char* wsp = (char*)d_ws;
    size_t off = 0;
    auto alloc = [&](size_t bytes) { void* p = wsp + off; off += (bytes + 255) & ~(size_t)255; return p; };
    int*   top0    = (int*)alloc(B_ * 4);
    int*   top1    = (int*)alloc(B_ * 4);
    int*   dis     = (int*)alloc(B_ * DISK_ * 4);
    float* d_table = (float*)alloc((size_t)R_ * F_ * 4);
    float* P1      = (float*)alloc((size_t)R_ * H_ * 4);
    float* P2      = (float*)alloc((size_t)R_ * H_ * 4);
    float* P3      = (float*)alloc((size_t)R_ * H_ * 4);
    float* ipost   = (float*)alloc((size_t)R_ * H_ * 4);
    short* Wt_mu   = (short*)alloc((size_t)512 * 512 * 2);
    short* Wt_ls   = (short*)alloc((size_t)512 * 512 * 2);
    short* Wt_3    = (short*)alloc((size_t)512 * 512 * 2);
    short* Wt_z1   = (short*)alloc((size_t)512 * 512 * 2);
    short* Wt_z2   = (short*)alloc((size_t)512 * 512 * 2);
    short* Wt_4    = (short*)alloc((size_t)320 * 512 * 2);
    float* buf1    = (float*)alloc((size_t)B_ * H_ * 4);   // mu
    float* buf2    = (float*)alloc((size_t)B_ * H_ * 4);   // ls
    short* bfA     = (short*)alloc((size_t)B_ * H_ * 2);   // h1 -> h3
    short* bfB     = (short*)alloc((size_t)B_ * H_ * 2);   // z  -> t
    short* bfC     = (short*)alloc((size_t)B_ * H_ * 2);   // z_

    init_kernel<<<3, 256, 0, stream>>>(out);
    topk_kernel<<<B_, 64, 0, stream>>>(logits, top0, top1, dis);
    tables_kernel<<<R_ / RPB, 256, 0, stream>>>(rels, rel_dict, W1, W3, iW1, ib1,
                                                iW2, ib2, d_table, P1, P2, P3, ipost);
    dim3 t16(16, 16), t10(16, 10);
    transpose_w<<<t16, 256, 0, stream>>>(Wmu, Wt_mu, 512, 512, 512);
    transpose_w<<<t16, 256, 0, stream>>>(Wls, Wt_ls, 512, 512, 512);
    transpose_w<<<t16, 256, 0, stream>>>(W3,  Wt_3,  512, 512, 512);  // rows 0..511 (z part)
    transpose_w<<<t16, 256, 0, stream>>>(zW1, Wt_z1, 512, 512, 512);
    transpose_w<<<t16, 256, 0, stream>>>(zW2, Wt_z2, 512, 512, 512);
    transpose_w<<<t10, 256, 0, stream>>>(W4,  Wt_4,  512, 300, 320);

    h1_kernel<<<B_ * H_ / 256, 256, 0, stream>>>(P1, P2, b1, top0, top1, bfA);

    dim3 g8(8, 128), g5(5, 128);
    // mu, ls
    gemm_mfma<0><<<g8, 256, 0, stream>>>(bfA, Wt_mu, buf1, bmu, nullptr, 0, nullptr, nullptr, 512);
    gemm_mfma<0><<<g8, 256, 0, stream>>>(bfA, Wt_ls, buf2, bls, nullptr, 0, nullptr, nullptr, 512);
    // z, z_, kl
    zkl_kernel<<<2048, 256, 0, stream>>>(buf1, buf2, eps1, eps2, bfB, bfC, out);
    // h3 = leaky(z @ W3[:512] + P3[top1] + b3)
    gemm_mfma<1><<<g8, 256, 0, stream>>>(bfB, Wt_3, bfA, b3, P3, 512, top1, nullptr, 512);
    // recon loss
    gemm_mfma<3><<<g5, 256, 0, stream>>>(bfA, Wt_4, nullptr, b4, d_table, 300, top0, out, 300);
    // t = relu(z_ @ zW1 + zb1)
    gemm_mfma<2><<<g8, 256, 0, stream>>>(bfC, Wt_z1, bfB, zb1, nullptr, 0, nullptr, nullptr, 512);
    // z_p = relu(t @ zW2 + zb2) -> z_rel rows 1..B
    gemm_mfma<4><<<g8, 256, 0, stream>>>(bfB, Wt_z2, out + 2 + L_, zb2, nullptr, 0, nullptr, nullptr, 512);
    // contrastive loss
    csl_kernel<<<B_ / 4, 256, 0, stream>>>(out + 2 + L_, ipost, top0, dis, out + 1);
}

// Round 3
// 721.789 us; speedup vs baseline: 2.0753x; 1.3293x over previous
//
#include <hip/hip_runtime.h>
#include <math.h>

#define B_ 16384
#define R_ 512
#define V_ 1000
#define F_ 300
#define L_ 512
#define H_ 512
#define LEAK_ 0.2f
#define TEMP_ 0.07f
#define DISK_ 15

#define NCSL_BLK (B_ / 4)      // 4096
#define NKL_BLK  2048
#define NREC_BLK (5 * 128)     // 640

typedef short short8 __attribute__((ext_vector_type(8)));
typedef float float4v __attribute__((ext_vector_type(4)));

__device__ __forceinline__ float waveReduceSum(float v) {
#pragma unroll
    for (int off = 32; off; off >>= 1) v += __shfl_xor(v, off);
    return v;
}

__device__ __forceinline__ short f2bf(float f) {
    unsigned u = __float_as_uint(f);
    unsigned r = (u + 0x7FFFu + ((u >> 16) & 1u)) >> 16;
    return (short)r;
}

// ---------------------------------------------------------------------------
// init: zero z_rel row 0 (losses are written by finalize_kernel)
// ---------------------------------------------------------------------------
__global__ void init_kernel(float* __restrict__ out) {
    int i = blockIdx.x * blockDim.x + threadIdx.x;
    if (i < 2 + L_) out[i] = 0.f;
}

// ---------------------------------------------------------------------------
// top-2 / bottom-15 per row. one wave per row.
// ---------------------------------------------------------------------------
__global__ __launch_bounds__(64) void topk_kernel(
    const float* __restrict__ logits, int* __restrict__ top0,
    int* __restrict__ top1, int* __restrict__ dis) {
    int b = blockIdx.x;
    int lane = threadIdx.x;
    const float* lp = logits + (size_t)b * R_;
    float v[8];
#pragma unroll
    for (int i = 0; i < 8; ++i) v[i] = lp[i * 64 + lane];

    int t0 = 0, t1 = 0;
#pragma unroll
    for (int pass = 0; pass < 2; ++pass) {
        float bv = -INFINITY; int bi = R_;
#pragma unroll
        for (int i = 0; i < 8; ++i) {
            int idx = i * 64 + lane;
            if (v[i] > bv || (v[i] == bv && idx < bi)) { bv = v[i]; bi = idx; }
        }
#pragma unroll
        for (int off = 32; off; off >>= 1) {
            float ov = __shfl_xor(bv, off);
            int   oi = __shfl_xor(bi, off);
            if (ov > bv || (ov == bv && oi < bi)) { bv = ov; bi = oi; }
        }
        if (pass == 0) t0 = bi; else t1 = bi;
        if ((bi & 63) == lane) v[bi >> 6] = -INFINITY;
    }
    if ((t0 & 63) == lane) v[t0 >> 6] = INFINITY;
    if ((t1 & 63) == lane) v[t1 >> 6] = INFINITY;

    int dloc[DISK_];
#pragma unroll
    for (int t = 0; t < DISK_; ++t) {
        float bv = INFINITY; int bi = R_;
#pragma unroll
        for (int i = 0; i < 8; ++i) {
            int idx = i * 64 + lane;
            if (v[i] < bv || (v[i] == bv && idx < bi)) { bv = v[i]; bi = idx; }
        }
#pragma unroll
        for (int off = 32; off; off >>= 1) {
            float ov = __shfl_xor(bv, off);
            int   oi = __shfl_xor(bi, off);
            if (ov < bv || (ov == bv && oi < bi)) { bv = ov; bi = oi; }
        }
        dloc[t] = bi;
        if ((bi & 63) == lane) v[bi >> 6] = INFINITY;
    }
    if (lane == 0) {
        top0[b] = t0; top1[b] = t1;
#pragma unroll
        for (int t = 0; t < DISK_; ++t) dis[b * DISK_ + t] = dloc[t];
    }
}

// ---------------------------------------------------------------------------
// per-relation tables: d[r], P1=d@W1a, P2=d@W1b, P3=d@W3b, ipost=mlp2(d)
// ---------------------------------------------------------------------------
#define RPB 4
__global__ __launch_bounds__(256) void tables_kernel(
    const int* __restrict__ rels32, const float* __restrict__ rel_dict,
    const float* __restrict__ W1, const float* __restrict__ W3,
    const float* __restrict__ iW1, const float* __restrict__ ib1,
    const float* __restrict__ iW2, const float* __restrict__ ib2,
    float* __restrict__ d_table, float* __restrict__ P1,
    float* __restrict__ P2, float* __restrict__ P3,
    float* __restrict__ ipost) {
    __shared__ float dl[RPB][F_];
    __shared__ float hl[RPB][H_];
    __shared__ int s_i64;
    int tid = threadIdx.x;
    int r0 = blockIdx.x * RPB;

    if (tid == 0) s_i64 = 1;
    __syncthreads();
    if (rels32[2 * tid + 1] != 0) s_i64 = 0;
    __syncthreads();
    int i64 = s_i64;

    for (int e = tid; e < RPB * F_; e += 256) {
        int r = e / F_, k = e - r * F_;
        int rr = r0 + r;
        int key = i64 ? rels32[4 * rr + 2] : rels32[2 * rr + 1];
        float val = rel_dict[key * F_ + k];
        dl[r][k] = val;
        d_table[rr * F_ + k] = val;
    }
    __syncthreads();

    for (int j = tid; j < H_; j += 256) {
        float a1[RPB] = {}, a2[RPB] = {}, a3[RPB] = {}, ai[RPB] = {};
        for (int k = 0; k < F_; ++k) {
            float w1a = W1[k * H_ + j];
            float w1b = W1[(F_ + k) * H_ + j];
            float w3  = W3[(L_ + k) * H_ + j];
            float wi  = iW1[k * H_ + j];
#pragma unroll
            for (int r = 0; r < RPB; ++r) {
                float dv = dl[r][k];
                a1[r] += dv * w1a; a2[r] += dv * w1b;
                a3[r] += dv * w3;  ai[r] += dv * wi;
            }
        }
#pragma unroll
        for (int r = 0; r < RPB; ++r) {
            P1[(r0 + r) * H_ + j] = a1[r];
            P2[(r0 + r) * H_ + j] = a2[r];
            P3[(r0 + r) * H_ + j] = a3[r];
            float h = ai[r] + ib1[j];
            hl[r][j] = h > 0.f ? h : 0.f;
        }
    }
    __syncthreads();

    for (int j = tid; j < H_; j += 256) {
        float acc[RPB] = {};
        for (int k = 0; k < H_; ++k) {
            float w = iW2[k * H_ + j];
#pragma unroll
            for (int r = 0; r < RPB; ++r) acc[r] += hl[r][k] * w;
        }
#pragma unroll
        for (int r = 0; r < RPB; ++r) {
            float vv = acc[r] + ib2[j];
            ipost[(r0 + r) * H_ + j] = vv > 0.f ? vv : 0.f;
        }
    }
}

// ---------------------------------------------------------------------------
// fused transpose of all 6 weight mats: fp32 W[512][N] -> bf16 Wt[Npad][512]
// grid (16, 16, 6)
// ---------------------------------------------------------------------------
struct TransArgs {
    const float* W[6];
    short* Wt[6];
    int N[6];
    int Npad[6];
};
__global__ __launch_bounds__(256) void transpose_all(TransArgs ta) {
    const int K = 512;
    int z = blockIdx.z;
    const float* W = ta.W[z];
    short* Wt = ta.Wt[z];
    int N = ta.N[z], Npad = ta.Npad[z];
    int n0 = blockIdx.y * 32;
    if (n0 >= Npad) return;
    __shared__ float tile[32][33];
    int tx = threadIdx.x & 31, ty = threadIdx.x >> 5;
    int k0 = blockIdx.x * 32;
#pragma unroll
    for (int i = 0; i < 4; ++i) {
        int k = k0 + i * 8 + ty, n = n0 + tx;
        tile[i * 8 + ty][tx] = (n < N) ? W[(size_t)k * N + n] : 0.f;
    }
    __syncthreads();
#pragma unroll
    for (int i = 0; i < 4; ++i) {
        int n = n0 + i * 8 + ty, k = k0 + tx;
        if (n < Npad) Wt[(size_t)n * K + k] = f2bf(tile[tx][i * 8 + ty]);
    }
}

// ---------------------------------------------------------------------------
// h1 = leaky(P1[top0] + P2[top1] + b1)  -> bf16
// ---------------------------------------------------------------------------
__global__ __launch_bounds__(256) void h1_kernel(
    const float* __restrict__ P1, const float* __restrict__ P2,
    const float* __restrict__ b1, const int* __restrict__ top0,
    const int* __restrict__ top1, short* __restrict__ h1b) {
    int idx = blockIdx.x * 256 + threadIdx.x;
    int b = idx >> 9, j = idx & 511;
    float v = P1[top0[b] * H_ + j] + P2[top1[b] * H_ + j] + b1[j];
    h1b[idx] = f2bf(v > 0.f ? v : LEAK_ * v);
}

// ---------------------------------------------------------------------------
// z / z_ (bf16) + kl partial per block (no atomics)
// ---------------------------------------------------------------------------
__global__ __launch_bounds__(256) void zkl_kernel(
    const float* __restrict__ mu, const float* __restrict__ ls,
    const float* __restrict__ eps1, const float* __restrict__ eps2,
    short* __restrict__ zb, short* __restrict__ z_b,
    float* __restrict__ partial_kl) {
    int idx = blockIdx.x * 256 + threadIdx.x;
    int stride = gridDim.x * 256;
    float kl = 0.f;
    for (int i = idx; i < B_ * L_; i += stride) {
        float m = mu[i], l = ls[i];
        float s = __expf(l);
        zb[i]  = f2bf(m + eps1[i] * s);
        z_b[i] = f2bf(m + eps2[i] * s);
        kl += -0.5f * (1.f + 2.f * l - m * m - s * s);
    }
    __shared__ float red[4];
    kl = waveReduceSum(kl);
    int lane = threadIdx.x & 63, w = threadIdx.x >> 6;
    if (lane == 0) red[w] = kl;
    __syncthreads();
    if (threadIdx.x == 0)
        partial_kl[blockIdx.x] = red[0] + red[1] + red[2] + red[3];
}

// ---------------------------------------------------------------------------
// bf16 MFMA GEMM: C[M,*] = A[M,512](bf16) @ Wt[N,512](bf16, pre-transposed)
// 256 thr (4 waves), tile 128(M) x 64(N), BK=32, double-buffered LDS.
//  EPI 0: fp32 store  acc + bias                       (mu, ls)
//  EPI 1: bf16 store  leaky(acc + bias + P3[rowsel])   (h3)
//  EPI 2: bf16 store  relu(acc + bias)                 (t)
//  EPI 3: partial[blk] = sum (tanh(acc+bias)-table[rowsel])^2   (recon)
//  EPI 4: fp32 store  relu(acc + bias)                 (z_p)
// ---------------------------------------------------------------------------
template <int EPI>
__global__ __launch_bounds__(256) void gemm_mfma(
    const short* __restrict__ A, const short* __restrict__ Wt,
    void* __restrict__ C, const float* __restrict__ bias,
    const float* __restrict__ table, int tld,
    const int* __restrict__ rowsel, float* __restrict__ lossp, int N) {
    __shared__ __align__(16) short Asl[2][128][40];
    __shared__ __align__(16) short Bsl[2][64][40];
    __shared__ float sred[4];
    const int K = 512;
    int tid = threadIdx.x;
    int lane = tid & 63, wv = tid >> 6;
    int lm = lane & 15, q = lane >> 4;
    int row0 = blockIdx.y * 128;
    int col0 = blockIdx.x * 64;

    float4v acc[2][4];
#pragma unroll
    for (int i = 0; i < 2; ++i)
#pragma unroll
        for (int j = 0; j < 4; ++j) acc[i][j] = {0.f, 0.f, 0.f, 0.f};

    uint4 aReg[2], bReg;
    int ar0 = tid >> 2, ak = (tid & 3) * 8;
    int ar1 = (tid + 256) >> 2;
    int br = tid >> 2, bk = (tid & 3) * 8;

    auto loadG = [&](int k0) {
        aReg[0] = *(const uint4*)&A[(size_t)(row0 + ar0) * K + k0 + ak];
        aReg[1] = *(const uint4*)&A[(size_t)(row0 + ar1) * K + k0 + ak];
        bReg    = *(const uint4*)&Wt[(size_t)(col0 + br) * K + k0 + bk];
    };
    auto storeL = [&](int p) {
        *(uint4*)&Asl[p][ar0][ak] = aReg[0];
        *(uint4*)&Asl[p][ar1][ak] = aReg[1];
        *(uint4*)&Bsl[p][br][bk]  = bReg;
    };

    int p = 0;
    loadG(0);
    storeL(0);
    for (int k0 = 0; k0 < K; k0 += 32) {
        __syncthreads();
        bool more = (k0 + 32) < K;
        if (more) loadG(k0 + 32);
        short8 af[2], bfr[4];
#pragma unroll
        for (int mt = 0; mt < 2; ++mt)
            af[mt] = *(const short8*)&Asl[p][wv * 32 + mt * 16 + lm][q * 8];
#pragma unroll
        for (int nt = 0; nt < 4; ++nt)
            bfr[nt] = *(const short8*)&Bsl[p][nt * 16 + lm][q * 8];
#pragma unroll
        for (int mt = 0; mt < 2; ++mt)
#pragma unroll
            for (int nt = 0; nt < 4; ++nt)
                acc[mt][nt] = __builtin_amdgcn_mfma_f32_16x16x32_bf16(
                    af[mt], bfr[nt], acc[mt][nt], 0, 0, 0);
        if (more) { p ^= 1; storeL(p); }
    }

    if (EPI == 3) {
        float lsum = 0.f;
#pragma unroll
        for (int mt = 0; mt < 2; ++mt) {
#pragma unroll
            for (int r = 0; r < 4; ++r) {
                int grow = row0 + wv * 32 + mt * 16 + q * 4 + r;
                int trow = rowsel[grow];
#pragma unroll
                for (int nt = 0; nt < 4; ++nt) {
                    int gcol = col0 + nt * 16 + lm;
                    if (gcol < N) {
                        float v = tanhf(acc[mt][nt][r] + bias[gcol]);
                        float d = v - table[(size_t)trow * tld + gcol];
                        lsum += d * d;
                    }
                }
            }
        }
        lsum = waveReduceSum(lsum);
        if (lane == 0) sred[wv] = lsum;
        __syncthreads();
        if (tid == 0)
            lossp[blockIdx.y * gridDim.x + blockIdx.x] =
                sred[0] + sred[1] + sred[2] + sred[3];
    } else {
#pragma unroll
        for (int mt = 0; mt < 2; ++mt) {
#pragma unroll
            for (int r = 0; r < 4; ++r) {
                int grow = row0 + wv * 32 + mt * 16 + q * 4 + r;
                int trow = (EPI == 1) ? rowsel[grow] : 0;
#pragma unroll
                for (int nt = 0; nt < 4; ++nt) {
                    int gcol = col0 + nt * 16 + lm;
                    float v = acc[mt][nt][r] + bias[gcol];
                    if (EPI == 1) {
                        v += table[(size_t)trow * tld + gcol];
                        v = v > 0.f ? v : LEAK_ * v;
                    }
                    if (EPI == 2 || EPI == 4) v = v > 0.f ? v : 0.f;
                    if (EPI == 0 || EPI == 4)
                        ((float*)C)[(size_t)grow * 512 + gcol] = v;
                    else
                        ((short*)C)[(size_t)grow * 512 + gcol] = f2bf(v);
                }
            }
        }
    }
}

// ---------------------------------------------------------------------------
// contrastive loss: one wave per row, per-block partial (no atomics)
// ---------------------------------------------------------------------------
__global__ __launch_bounds__(256) void csl_kernel(
    const float* __restrict__ zp, const float* __restrict__ ipost,
    const int* __restrict__ top0, const int* __restrict__ dis,
    float* __restrict__ partial_csl) {
    __shared__ float sred[4];
    int w = threadIdx.x >> 6, lane = threadIdx.x & 63;
    int b = blockIdx.x * 4 + w;
    const float* zr = zp + (size_t)b * 512;
    float z[8];
#pragma unroll
    for (int i = 0; i < 8; ++i) z[i] = zr[i * 64 + lane];
    int cand[16];
    cand[0] = top0[b];
#pragma unroll
    for (int n = 0; n < DISK_; ++n) cand[n + 1] = dis[b * DISK_ + n];
    float s[16];
#pragma unroll
    for (int c = 0; c < 16; ++c) {
        const float* ip = ipost + (size_t)cand[c] * 512;
        float a = 0.f;
#pragma unroll
        for (int i = 0; i < 8; ++i) a += z[i] * ip[i * 64 + lane];
        s[c] = a;
    }
#pragma unroll
    for (int off = 32; off; off >>= 1) {
        float o[16];
#pragma unroll
        for (int c = 0; c < 16; ++c) o[c] = __shfl_xor(s[c], off);
#pragma unroll
        for (int c = 0; c < 16; ++c) s[c] += o[c];
    }
    float loss = 0.f;
    if (lane == 0) {
        float m = s[0];
#pragma unroll
        for (int c = 1; c < 16; ++c) m = fmaxf(m, s[c]);
        float se = 0.f;
#pragma unroll
        for (int c = 0; c < 16; ++c) se += __expf((s[c] - m) / TEMP_);
        loss = -((s[0] - m) / TEMP_ - __logf(se));
        sred[w] = loss;
    }
    __syncthreads();
    if (threadIdx.x == 0)
        partial_csl[blockIdx.x] = sred[0] + sred[1] + sred[2] + sred[3];
}

// ---------------------------------------------------------------------------
// finalize: out[0] = sum(kl) + sum(recon); out[1] = sum(csl). one block.
// ---------------------------------------------------------------------------
__global__ __launch_bounds__(256) void finalize_kernel(
    const float* __restrict__ pkl, const float* __restrict__ prec,
    const float* __restrict__ pcsl, float* __restrict__ out) {
    __shared__ float red[4][2];
    int tid = threadIdx.x;
    float a0 = 0.f, a1 = 0.f;
    for (int i = tid; i < NKL_BLK; i += 256) a0 += pkl[i];
    for (int i = tid; i < NREC_BLK; i += 256) a0 += prec[i];
    for (int i = tid; i < NCSL_BLK; i += 256) a1 += pcsl[i];
    a0 = waveReduceSum(a0);
    a1 = waveReduceSum(a1);
    int lane = tid & 63, w = tid >> 6;
    if (lane == 0) { red[w][0] = a0; red[w][1] = a1; }
    __syncthreads();
    if (tid == 0) out[0] = red[0][0] + red[1][0] + red[2][0] + red[3][0];
    if (tid == 1) out[1] = red[0][1] + red[1][1] + red[2][1] + red[3][1];
}

// ---------------------------------------------------------------------------
extern "C" void kernel_launch(void* const* d_in, const int* in_sizes, int n_in,
                              void* d_out, int out_size, void* d_ws, size_t ws_size,
                              hipStream_t stream) {
    const float* logits  = (const float*)d_in[0];
    const int*   rels    = (const int*)d_in[1];
    const float* rel_dict= (const float*)d_in[2];
    const float* eps1    = (const float*)d_in[3];
    const float* eps2    = (const float*)d_in[4];
    const float* W1  = (const float*)d_in[5];
    const float* b1  = (const float*)d_in[6];
    const float* Wmu = (const float*)d_in[7];
    const float* bmu = (const float*)d_in[8];
    const float* Wls = (const float*)d_in[9];
    const float* bls = (const float*)d_in[10];
    const float* W3  = (const float*)d_in[11];
    const float* b3  = (const float*)d_in[12];
    const float* W4  = (const float*)d_in[13];
    const float* b4  = (const float*)d_in[14];
    const float* iW1 = (const float*)d_in[15];
    const float* ib1 = (const float*)d_in[16];
    const float* iW2 = (const float*)d_in[17];
    const float* ib2 = (const float*)d_in[18];
    const float* zW1 = (const float*)d_in[19];
    const float* zb1 = (const float*)d_in[20];
    const float* zW2 = (const float*)d_in[21];
    const float* zb2 = (const float*)d_in[22];
    float* out = (float*)d_out;

    char* wsp = (char*)d_ws;
    size_t off = 0;
    auto alloc = [&](size_t bytes) { void* p = wsp + off; off += (bytes + 255) & ~(size_t)255; return p; };
    int*   top0    = (int*)alloc(B_ * 4);
    int*   top1    = (int*)alloc(B_ * 4);
    int*   dis     = (int*)alloc(B_ * DISK_ * 4);
    float* d_table = (float*)alloc((size_t)R_ * F_ * 4);
    float* P1      = (float*)alloc((size_t)R_ * H_ * 4);
    float* P2      = (float*)alloc((size_t)R_ * H_ * 4);
    float* P3      = (float*)alloc((size_t)R_ * H_ * 4);
    float* ipost   = (float*)alloc((size_t)R_ * H_ * 4);
    short* Wt_mu   = (short*)alloc((size_t)512 * 512 * 2);
    short* Wt_ls   = (short*)alloc((size_t)512 * 512 * 2);
    short* Wt_3    = (short*)alloc((size_t)512 * 512 * 2);
    short* Wt_z1   = (short*)alloc((size_t)512 * 512 * 2);
    short* Wt_z2   = (short*)alloc((size_t)512 * 512 * 2);
    short* Wt_4    = (short*)alloc((size_t)320 * 512 * 2);
    float* buf1    = (float*)alloc((size_t)B_ * H_ * 4);   // mu
    float* buf2    = (float*)alloc((size_t)B_ * H_ * 4);   // ls
    short* bfA     = (short*)alloc((size_t)B_ * H_ * 2);   // h1 -> h3
    short* bfB     = (short*)alloc((size_t)B_ * H_ * 2);   // z  -> t
    short* bfC     = (short*)alloc((size_t)B_ * H_ * 2);   // z_
    float* p_csl   = (float*)alloc(NCSL_BLK * 4);
    float* p_kl    = (float*)alloc(NKL_BLK * 4);
    float* p_rec   = (float*)alloc(NREC_BLK * 4);

    init_kernel<<<3, 256, 0, stream>>>(out);
    topk_kernel<<<B_, 64, 0, stream>>>(logits, top0, top1, dis);
    tables_kernel<<<R_ / RPB, 256, 0, stream>>>(rels, rel_dict, W1, W3, iW1, ib1,
                                                iW2, ib2, d_table, P1, P2, P3, ipost);
    TransArgs ta;
    ta.W[0] = Wmu; ta.Wt[0] = Wt_mu; ta.N[0] = 512; ta.Npad[0] = 512;
    ta.W[1] = Wls; ta.Wt[1] = Wt_ls; ta.N[1] = 512; ta.Npad[1] = 512;
    ta.W[2] = W3;  ta.Wt[2] = Wt_3;  ta.N[2] = 512; ta.Npad[2] = 512;
    ta.W[3] = zW1; ta.Wt[3] = Wt_z1; ta.N[3] = 512; ta.Npad[3] = 512;
    ta.W[4] = zW2; ta.Wt[4] = Wt_z2; ta.N[4] = 512; ta.Npad[4] = 512;
    ta.W[5] = W4;  ta.Wt[5] = Wt_4;  ta.N[5] = 300; ta.Npad[5] = 320;
    transpose_all<<<dim3(16, 16, 6), 256, 0, stream>>>(ta);

    h1_kernel<<<B_ * H_ / 256, 256, 0, stream>>>(P1, P2, b1, top0, top1, bfA);

    dim3 g8(8, 128), g5(5, 128);
    gemm_mfma<0><<<g8, 256, 0, stream>>>(bfA, Wt_mu, buf1, bmu, nullptr, 0, nullptr, nullptr, 512);
    gemm_mfma<0><<<g8, 256, 0, stream>>>(bfA, Wt_ls, buf2, bls, nullptr, 0, nullptr, nullptr, 512);
    zkl_kernel<<<NKL_BLK, 256, 0, stream>>>(buf1, buf2, eps1, eps2, bfB, bfC, p_kl);
    gemm_mfma<1><<<g8, 256, 0, stream>>>(bfB, Wt_3, bfA, b3, P3, 512, top1, nullptr, 512);
    gemm_mfma<3><<<g5, 256, 0, stream>>>(bfA, Wt_4, nullptr, b4, d_table, 300, top0, p_rec, 300);
    gemm_mfma<2><<<g8, 256, 0, stream>>>(bfC, Wt_z1, bfB, zb1, nullptr, 0, nullptr, nullptr, 512);
    gemm_mfma<4><<<g8, 256, 0, stream>>>(bfB, Wt_z2, out + 2 + L_, zb2, nullptr, 0, nullptr, nullptr, 512);
    csl_kernel<<<NCSL_BLK, 256, 0, stream>>>(out + 2 + L_, ipost, top0, dis, p_csl);
    finalize_kernel<<<1, 256, 0, stream>>>(p_kl, p_rec, p_csl, out);
}

// Round 4
// 555.368 us; speedup vs baseline: 2.6972x; 1.2997x over previous
//
#include <hip/hip_runtime.h>
#include <math.h>

#define B_ 16384
#define R_ 512
#define V_ 1000
#define F_ 300
#define FP_ 320           // F padded to multiple of 32
#define L_ 512
#define H_ 512
#define LEAK_ 0.2f
#define TEMP_ 0.07f
#define DISK_ 15

#define NCSL_BLK (B_ / 4)      // 4096
#define NKL_BLK  2048
#define NREC_BLK (5 * 128)     // 640

typedef short short8 __attribute__((ext_vector_type(8)));
typedef float float4v __attribute__((ext_vector_type(4)));

__device__ __forceinline__ float waveReduceSum(float v) {
#pragma unroll
    for (int off = 32; off; off >>= 1) v += __shfl_xor(v, off);
    return v;
}

__device__ __forceinline__ short f2bf(float f) {
    unsigned u = __float_as_uint(f);
    unsigned r = (u + 0x7FFFu + ((u >> 16) & 1u)) >> 16;
    return (short)r;
}

// ---------------------------------------------------------------------------
// init: zero z_rel row 0 (losses are written by finalize_kernel)
// ---------------------------------------------------------------------------
__global__ void init_kernel(float* __restrict__ out) {
    int i = blockIdx.x * blockDim.x + threadIdx.x;
    if (i < 2 + L_) out[i] = 0.f;
}

// ---------------------------------------------------------------------------
// top-2 / bottom-15 per row. one wave per row.
// ---------------------------------------------------------------------------
__global__ __launch_bounds__(64) void topk_kernel(
    const float* __restrict__ logits, int* __restrict__ top0,
    int* __restrict__ top1, int* __restrict__ dis) {
    int b = blockIdx.x;
    int lane = threadIdx.x;
    const float* lp = logits + (size_t)b * R_;
    float v[8];
#pragma unroll
    for (int i = 0; i < 8; ++i) v[i] = lp[i * 64 + lane];

    int t0 = 0, t1 = 0;
#pragma unroll
    for (int pass = 0; pass < 2; ++pass) {
        float bv = -INFINITY; int bi = R_;
#pragma unroll
        for (int i = 0; i < 8; ++i) {
            int idx = i * 64 + lane;
            if (v[i] > bv || (v[i] == bv && idx < bi)) { bv = v[i]; bi = idx; }
        }
#pragma unroll
        for (int off = 32; off; off >>= 1) {
            float ov = __shfl_xor(bv, off);
            int   oi = __shfl_xor(bi, off);
            if (ov > bv || (ov == bv && oi < bi)) { bv = ov; bi = oi; }
        }
        if (pass == 0) t0 = bi; else t1 = bi;
        if ((bi & 63) == lane) v[bi >> 6] = -INFINITY;
    }
    if ((t0 & 63) == lane) v[t0 >> 6] = INFINITY;
    if ((t1 & 63) == lane) v[t1 >> 6] = INFINITY;

    int dloc[DISK_];
#pragma unroll
    for (int t = 0; t < DISK_; ++t) {
        float bv = INFINITY; int bi = R_;
#pragma unroll
        for (int i = 0; i < 8; ++i) {
            int idx = i * 64 + lane;
            if (v[i] < bv || (v[i] == bv && idx < bi)) { bv = v[i]; bi = idx; }
        }
#pragma unroll
        for (int off = 32; off; off >>= 1) {
            float ov = __shfl_xor(bv, off);
            int   oi = __shfl_xor(bi, off);
            if (ov < bv || (ov == bv && oi < bi)) { bv = ov; bi = oi; }
        }
        dloc[t] = bi;
        if ((bi & 63) == lane) v[bi >> 6] = INFINITY;
    }
    if (lane == 0) {
        top0[b] = t0; top1[b] = t1;
#pragma unroll
        for (int t = 0; t < DISK_; ++t) dis[b * DISK_ + t] = dloc[t];
    }
}

// ---------------------------------------------------------------------------
// gather d_table (fp32) + dt bf16 padded to FP_ cols. one block per relation.
// ---------------------------------------------------------------------------
__global__ __launch_bounds__(FP_) void gather_d(
    const int* __restrict__ rels32, const float* __restrict__ rel_dict,
    float* __restrict__ d_table, short* __restrict__ dt) {
    __shared__ int s_i64;
    int tid = threadIdx.x, r = blockIdx.x;
    if (tid == 0) s_i64 = 1;
    __syncthreads();
    if (rels32[2 * tid + 1] != 0) s_i64 = 0;
    __syncthreads();
    int key = s_i64 ? rels32[4 * r + 2] : rels32[2 * r + 1];
    if (tid < F_) {
        float v = rel_dict[(size_t)key * F_ + tid];
        d_table[(size_t)r * F_ + tid] = v;
        dt[(size_t)r * FP_ + tid] = f2bf(v);
    } else {
        dt[(size_t)r * FP_ + tid] = 0;
    }
}

// ---------------------------------------------------------------------------
// fused transpose of 11 weight views: fp32 W[row_off+K][N] -> bf16 Wt[Npad][Kpad]
// grid (16, 16, 11); early-return on out-of-range tiles.
// ---------------------------------------------------------------------------
#define NT_ 11
struct TransArgs {
    const float* W[NT_];
    short* Wt[NT_];
    int row_off[NT_];
    int K[NT_];
    int Kpad[NT_];
    int N[NT_];
    int Npad[NT_];
};
__global__ __launch_bounds__(256) void transpose_all(TransArgs ta) {
    int z = blockIdx.z;
    const float* W = ta.W[z];
    short* Wt = ta.Wt[z];
    int row_off = ta.row_off[z];
    int K = ta.K[z], Kpad = ta.Kpad[z], N = ta.N[z], Npad = ta.Npad[z];
    int k0 = blockIdx.x * 32, n0 = blockIdx.y * 32;
    if (k0 >= Kpad || n0 >= Npad) return;
    __shared__ float tile[32][33];
    int tx = threadIdx.x & 31, ty = threadIdx.x >> 5;
#pragma unroll
    for (int i = 0; i < 4; ++i) {
        int k = k0 + i * 8 + ty, n = n0 + tx;
        tile[i * 8 + ty][tx] = (k < K && n < N) ? W[(size_t)(row_off + k) * N + n] : 0.f;
    }
    __syncthreads();
#pragma unroll
    for (int i = 0; i < 4; ++i) {
        int n = n0 + i * 8 + ty, k = k0 + tx;
        if (n < Npad && k < Kpad) Wt[(size_t)n * Kpad + k] = f2bf(tile[tx][i * 8 + ty]);
    }
}

// ---------------------------------------------------------------------------
// h1 = leaky(Pcat[top0,0:512] + Pcat[top1,512:1024] + b1)  -> bf16
// ---------------------------------------------------------------------------
__global__ __launch_bounds__(256) void h1_kernel(
    const float* __restrict__ Pcat, const float* __restrict__ b1,
    const int* __restrict__ top0, const int* __restrict__ top1,
    short* __restrict__ h1b) {
    int idx = blockIdx.x * 256 + threadIdx.x;
    int b = idx >> 9, j = idx & 511;
    float v = Pcat[(size_t)top0[b] * 2048 + j] + Pcat[(size_t)top1[b] * 2048 + 512 + j] + b1[j];
    h1b[idx] = f2bf(v > 0.f ? v : LEAK_ * v);
}

// ---------------------------------------------------------------------------
// ipre = relu(Pcat[:,1536:2048] + ib1) -> bf16
// ---------------------------------------------------------------------------
__global__ __launch_bounds__(256) void ipre_kernel(
    const float* __restrict__ Pcat, const float* __restrict__ ib1,
    short* __restrict__ ipre) {
    int idx = blockIdx.x * 256 + threadIdx.x;   // R_*512 total
    int r = idx >> 9, j = idx & 511;
    float v = Pcat[(size_t)r * 2048 + 1536 + j] + ib1[j];
    ipre[idx] = f2bf(v > 0.f ? v : 0.f);
}

// ---------------------------------------------------------------------------
// z / z_ (bf16) + kl partial per block (no atomics)
// ---------------------------------------------------------------------------
__global__ __launch_bounds__(256) void zkl_kernel(
    const float* __restrict__ mu, const float* __restrict__ ls,
    const float* __restrict__ eps1, const float* __restrict__ eps2,
    short* __restrict__ zb, short* __restrict__ z_b,
    float* __restrict__ partial_kl) {
    int idx = blockIdx.x * 256 + threadIdx.x;
    int stride = gridDim.x * 256;
    float kl = 0.f;
    for (int i = idx; i < B_ * L_; i += stride) {
        float m = mu[i], l = ls[i];
        float s = __expf(l);
        zb[i]  = f2bf(m + eps1[i] * s);
        z_b[i] = f2bf(m + eps2[i] * s);
        kl += -0.5f * (1.f + 2.f * l - m * m - s * s);
    }
    __shared__ float red[4];
    kl = waveReduceSum(kl);
    int lane = threadIdx.x & 63, w = threadIdx.x >> 6;
    if (lane == 0) red[w] = kl;
    __syncthreads();
    if (threadIdx.x == 0)
        partial_kl[blockIdx.x] = red[0] + red[1] + red[2] + red[3];
}

// ---------------------------------------------------------------------------
// bf16 MFMA GEMM: C[M,*] = A[M,KK](bf16) @ Wt[N,KK](bf16, pre-transposed)
// 256 thr (4 waves), tile 128(M) x 64(N), BK=32, double-buffered LDS.
//  EPI 0: fp32 store  acc + bias                       (mu, ls)
//  EPI 1: bf16 store  leaky(acc + bias + table[rowsel])(h3)
//  EPI 2: bf16 store  relu(acc + bias)                 (t)
//  EPI 3: partial[blk] = sum (tanh(acc+bias)-table[rowsel])^2   (recon)
//  EPI 4: fp32 store  relu(acc + bias)                 (z_p, ipost)
//  EPI 5: fp32 store  acc (no bias)                    (Pcat)
// ---------------------------------------------------------------------------
template <int EPI, int KK>
__global__ __launch_bounds__(256) void gemm_mfma(
    const short* __restrict__ A, const short* __restrict__ Wt,
    void* __restrict__ C, int ldc, const float* __restrict__ bias,
    const float* __restrict__ table, int tld,
    const int* __restrict__ rowsel, float* __restrict__ lossp, int N) {
    __shared__ __align__(16) short Asl[2][128][40];
    __shared__ __align__(16) short Bsl[2][64][40];
    __shared__ float sred[4];
    int tid = threadIdx.x;
    int lane = tid & 63, wv = tid >> 6;
    int lm = lane & 15, q = lane >> 4;
    int row0 = blockIdx.y * 128;
    int col0 = blockIdx.x * 64;

    float4v acc[2][4];
#pragma unroll
    for (int i = 0; i < 2; ++i)
#pragma unroll
        for (int j = 0; j < 4; ++j) acc[i][j] = {0.f, 0.f, 0.f, 0.f};

    uint4 aReg[2], bReg;
    int ar0 = tid >> 2, ak = (tid & 3) * 8;
    int ar1 = (tid + 256) >> 2;
    int br = tid >> 2, bk = (tid & 3) * 8;

    auto loadG = [&](int k0) {
        aReg[0] = *(const uint4*)&A[(size_t)(row0 + ar0) * KK + k0 + ak];
        aReg[1] = *(const uint4*)&A[(size_t)(row0 + ar1) * KK + k0 + ak];
        bReg    = *(const uint4*)&Wt[(size_t)(col0 + br) * KK + k0 + bk];
    };
    auto storeL = [&](int p) {
        *(uint4*)&Asl[p][ar0][ak] = aReg[0];
        *(uint4*)&Asl[p][ar1][ak] = aReg[1];
        *(uint4*)&Bsl[p][br][bk]  = bReg;
    };

    int p = 0;
    loadG(0);
    storeL(0);
    for (int k0 = 0; k0 < KK; k0 += 32) {
        __syncthreads();
        bool more = (k0 + 32) < KK;
        if (more) loadG(k0 + 32);
        short8 af[2], bfr[4];
#pragma unroll
        for (int mt = 0; mt < 2; ++mt)
            af[mt] = *(const short8*)&Asl[p][wv * 32 + mt * 16 + lm][q * 8];
#pragma unroll
        for (int nt = 0; nt < 4; ++nt)
            bfr[nt] = *(const short8*)&Bsl[p][nt * 16 + lm][q * 8];
#pragma unroll
        for (int mt = 0; mt < 2; ++mt)
#pragma unroll
            for (int nt = 0; nt < 4; ++nt)
                acc[mt][nt] = __builtin_amdgcn_mfma_f32_16x16x32_bf16(
                    af[mt], bfr[nt], acc[mt][nt], 0, 0, 0);
        if (more) { p ^= 1; storeL(p); }
    }

    if (EPI == 3) {
        float lsum = 0.f;
#pragma unroll
        for (int mt = 0; mt < 2; ++mt) {
#pragma unroll
            for (int r = 0; r < 4; ++r) {
                int grow = row0 + wv * 32 + mt * 16 + q * 4 + r;
                int trow = rowsel[grow];
#pragma unroll
                for (int nt = 0; nt < 4; ++nt) {
                    int gcol = col0 + nt * 16 + lm;
                    if (gcol < N) {
                        float v = tanhf(acc[mt][nt][r] + bias[gcol]);
                        float d = v - table[(size_t)trow * tld + gcol];
                        lsum += d * d;
                    }
                }
            }
        }
        lsum = waveReduceSum(lsum);
        if (lane == 0) sred[wv] = lsum;
        __syncthreads();
        if (tid == 0)
            lossp[blockIdx.y * gridDim.x + blockIdx.x] =
                sred[0] + sred[1] + sred[2] + sred[3];
    } else {
#pragma unroll
        for (int mt = 0; mt < 2; ++mt) {
#pragma unroll
            for (int r = 0; r < 4; ++r) {
                int grow = row0 + wv * 32 + mt * 16 + q * 4 + r;
                int trow = (EPI == 1) ? rowsel[grow] : 0;
#pragma unroll
                for (int nt = 0; nt < 4; ++nt) {
                    int gcol = col0 + nt * 16 + lm;
                    float v = acc[mt][nt][r];
                    if (EPI != 5) v += bias[gcol];
                    if (EPI == 1) {
                        v += table[(size_t)trow * tld + gcol];
                        v = v > 0.f ? v : LEAK_ * v;
                    }
                    if (EPI == 2 || EPI == 4) v = v > 0.f ? v : 0.f;
                    if (EPI == 0 || EPI == 4 || EPI == 5)
                        ((float*)C)[(size_t)grow * ldc + gcol] = v;
                    else
                        ((short*)C)[(size_t)grow * ldc + gcol] = f2bf(v);
                }
            }
        }
    }
}

// ---------------------------------------------------------------------------
// contrastive loss: one wave per row, per-block partial (no atomics)
// ---------------------------------------------------------------------------
__global__ __launch_bounds__(256) void csl_kernel(
    const float* __restrict__ zp, const float* __restrict__ ipost,
    const int* __restrict__ top0, const int* __restrict__ dis,
    float* __restrict__ partial_csl) {
    __shared__ float sred[4];
    int w = threadIdx.x >> 6, lane = threadIdx.x & 63;
    int b = blockIdx.x * 4 + w;
    const float* zr = zp + (size_t)b * 512;
    float z[8];
#pragma unroll
    for (int i = 0; i < 8; ++i) z[i] = zr[i * 64 + lane];
    int cand[16];
    cand[0] = top0[b];
#pragma unroll
    for (int n = 0; n < DISK_; ++n) cand[n + 1] = dis[b * DISK_ + n];
    float s[16];
#pragma unroll
    for (int c = 0; c < 16; ++c) {
        const float* ip = ipost + (size_t)cand[c] * 512;
        float a = 0.f;
#pragma unroll
        for (int i = 0; i < 8; ++i) a += z[i] * ip[i * 64 + lane];
        s[c] = a;
    }
#pragma unroll
    for (int off = 32; off; off >>= 1) {
        float o[16];
#pragma unroll
        for (int c = 0; c < 16; ++c) o[c] = __shfl_xor(s[c], off);
#pragma unroll
        for (int c = 0; c < 16; ++c) s[c] += o[c];
    }
    if (lane == 0) {
        float m = s[0];
#pragma unroll
        for (int c = 1; c < 16; ++c) m = fmaxf(m, s[c]);
        float se = 0.f;
#pragma unroll
        for (int c = 0; c < 16; ++c) se += __expf((s[c] - m) / TEMP_);
        sred[w] = -((s[0] - m) / TEMP_ - __logf(se));
    }
    __syncthreads();
    if (threadIdx.x == 0)
        partial_csl[blockIdx.x] = sred[0] + sred[1] + sred[2] + sred[3];
}

// ---------------------------------------------------------------------------
// finalize: out[0] = sum(kl) + sum(recon); out[1] = sum(csl). one block.
// ---------------------------------------------------------------------------
__global__ __launch_bounds__(256) void finalize_kernel(
    const float* __restrict__ pkl, const float* __restrict__ prec,
    const float* __restrict__ pcsl, float* __restrict__ out) {
    __shared__ float red[4][2];
    int tid = threadIdx.x;
    float a0 = 0.f, a1 = 0.f;
    for (int i = tid; i < NKL_BLK; i += 256) a0 += pkl[i];
    for (int i = tid; i < NREC_BLK; i += 256) a0 += prec[i];
    for (int i = tid; i < NCSL_BLK; i += 256) a1 += pcsl[i];
    a0 = waveReduceSum(a0);
    a1 = waveReduceSum(a1);
    int lane = tid & 63, w = tid >> 6;
    if (lane == 0) { red[w][0] = a0; red[w][1] = a1; }
    __syncthreads();
    if (tid == 0) out[0] = red[0][0] + red[1][0] + red[2][0] + red[3][0];
    if (tid == 1) out[1] = red[0][1] + red[1][1] + red[2][1] + red[3][1];
}

// ---------------------------------------------------------------------------
extern "C" void kernel_launch(void* const* d_in, const int* in_sizes, int n_in,
                              void* d_out, int out_size, void* d_ws, size_t ws_size,
                              hipStream_t stream) {
    const float* logits  = (const float*)d_in[0];
    const int*   rels    = (const int*)d_in[1];
    const float* rel_dict= (const float*)d_in[2];
    const float* eps1    = (const float*)d_in[3];
    const float* eps2    = (const float*)d_in[4];
    const float* W1  = (const float*)d_in[5];
    const float* b1  = (const float*)d_in[6];
    const float* Wmu = (const float*)d_in[7];
    const float* bmu = (const float*)d_in[8];
    const float* Wls = (const float*)d_in[9];
    const float* bls = (const float*)d_in[10];
    const float* W3  = (const float*)d_in[11];
    const float* b3  = (const float*)d_in[12];
    const float* W4  = (const float*)d_in[13];
    const float* b4  = (const float*)d_in[14];
    const float* iW1 = (const float*)d_in[15];
    const float* ib1 = (const float*)d_in[16];
    const float* iW2 = (const float*)d_in[17];
    const float* ib2 = (const float*)d_in[18];
    const float* zW1 = (const float*)d_in[19];
    const float* zb1 = (const float*)d_in[20];
    const float* zW2 = (const float*)d_in[21];
    const float* zb2 = (const float*)d_in[22];
    float* out = (float*)d_out;

    char* wsp = (char*)d_ws;
    size_t off = 0;
    auto alloc = [&](size_t bytes) { void* p = wsp + off; off += (bytes + 255) & ~(size_t)255; return p; };
    int*   top0    = (int*)alloc(B_ * 4);
    int*   top1    = (int*)alloc(B_ * 4);
    int*   dis     = (int*)alloc(B_ * DISK_ * 4);
    float* d_table = (float*)alloc((size_t)R_ * F_ * 4);
    short* dt      = (short*)alloc((size_t)R_ * FP_ * 2);
    short* Wcat_t  = (short*)alloc((size_t)2048 * FP_ * 2);
    float* Pcat    = (float*)alloc((size_t)R_ * 2048 * 4);
    short* ipre    = (short*)alloc((size_t)R_ * H_ * 2);
    float* ipost   = (float*)alloc((size_t)R_ * H_ * 4);
    short* Wt_mu   = (short*)alloc((size_t)512 * 512 * 2);
    short* Wt_ls   = (short*)alloc((size_t)512 * 512 * 2);
    short* Wt_3    = (short*)alloc((size_t)512 * 512 * 2);
    short* Wt_z1   = (short*)alloc((size_t)512 * 512 * 2);
    short* Wt_z2   = (short*)alloc((size_t)512 * 512 * 2);
    short* Wt_4    = (short*)alloc((size_t)320 * 512 * 2);
    short* Wt_i2   = (short*)alloc((size_t)512 * 512 * 2);
    float* buf1    = (float*)alloc((size_t)B_ * H_ * 4);   // mu
    float* buf2    = (float*)alloc((size_t)B_ * H_ * 4);   // ls
    short* bfA     = (short*)alloc((size_t)B_ * H_ * 2);   // h1 -> h3
    short* bfB     = (short*)alloc((size_t)B_ * H_ * 2);   // z  -> t
    short* bfC     = (short*)alloc((size_t)B_ * H_ * 2);   // z_
    float* p_csl   = (float*)alloc(NCSL_BLK * 4);
    float* p_kl    = (float*)alloc(NKL_BLK * 4);
    float* p_rec   = (float*)alloc(NREC_BLK * 4);

    init_kernel<<<3, 256, 0, stream>>>(out);
    topk_kernel<<<B_, 64, 0, stream>>>(logits, top0, top1, dis);
    gather_d<<<R_, FP_, 0, stream>>>(rels, rel_dict, d_table, dt);

    TransArgs ta;
    auto set = [&](int i, const float* W, short* Wt, int ro, int K, int Kp, int N, int Np) {
        ta.W[i] = W; ta.Wt[i] = Wt; ta.row_off[i] = ro; ta.K[i] = K;
        ta.Kpad[i] = Kp; ta.N[i] = N; ta.Npad[i] = Np;
    };
    set(0, Wmu, Wt_mu, 0, 512, 512, 512, 512);
    set(1, Wls, Wt_ls, 0, 512, 512, 512, 512);
    set(2, W3,  Wt_3,  0, 512, 512, 512, 512);
    set(3, zW1, Wt_z1, 0, 512, 512, 512, 512);
    set(4, zW2, Wt_z2, 0, 512, 512, 512, 512);
    set(5, W4,  Wt_4,  0, 512, 512, 300, 320);
    set(6, W1,  Wcat_t,                 0,   F_, FP_, 512, 512);   // P1 weights
    set(7, W1,  Wcat_t + 512 * FP_,     F_,  F_, FP_, 512, 512);   // P2 weights
    set(8, W3,  Wcat_t + 1024 * FP_,    L_,  F_, FP_, 512, 512);   // P3 weights
    set(9, iW1, Wcat_t + 1536 * FP_,    0,   F_, FP_, 512, 512);   // ipre weights
    set(10, iW2, Wt_i2, 0, 512, 512, 512, 512);
    transpose_all<<<dim3(16, 16, NT_), 256, 0, stream>>>(ta);

    // Pcat[512][2048] = dt @ Wcat  (no bias)
    gemm_mfma<5, FP_><<<dim3(32, 4), 256, 0, stream>>>(
        dt, Wcat_t, Pcat, 2048, nullptr, nullptr, 0, nullptr, nullptr, 2048);
    ipre_kernel<<<R_ * H_ / 256, 256, 0, stream>>>(Pcat, ib1, ipre);
    // ipost = relu(ipre @ iW2 + ib2)  fp32
    gemm_mfma<4, 512><<<dim3(8, 4), 256, 0, stream>>>(
        ipre, Wt_i2, ipost, 512, ib2, nullptr, 0, nullptr, nullptr, 512);

    h1_kernel<<<B_ * H_ / 256, 256, 0, stream>>>(Pcat, b1, top0, top1, bfA);

    dim3 g8(8, 128), g5(5, 128);
    gemm_mfma<0, 512><<<g8, 256, 0, stream>>>(bfA, Wt_mu, buf1, 512, bmu, nullptr, 0, nullptr, nullptr, 512);
    gemm_mfma<0, 512><<<g8, 256, 0, stream>>>(bfA, Wt_ls, buf2, 512, bls, nullptr, 0, nullptr, nullptr, 512);
    zkl_kernel<<<NKL_BLK, 256, 0, stream>>>(buf1, buf2, eps1, eps2, bfB, bfC, p_kl);
    // h3 = leaky(z @ W3[:512] + Pcat[top1,1024:1536] + b3)
    gemm_mfma<1, 512><<<g8, 256, 0, stream>>>(bfB, Wt_3, bfA, 512, b3, Pcat + 1024, 2048, top1, nullptr, 512);
    gemm_mfma<3, 512><<<g5, 256, 0, stream>>>(bfA, Wt_4, nullptr, 0, b4, d_table, F_, top0, p_rec, 300);
    gemm_mfma<2, 512><<<g8, 256, 0, stream>>>(bfC, Wt_z1, bfB, 512, zb1, nullptr, 0, nullptr, nullptr, 512);
    gemm_mfma<4, 512><<<g8, 256, 0, stream>>>(bfB, Wt_z2, out + 2 + L_, 512, zb2, nullptr, 0, nullptr, nullptr, 512);
    csl_kernel<<<NCSL_BLK, 256, 0, stream>>>(out + 2 + L_, ipost, top0, dis, p_csl);
    finalize_kernel<<<1, 256, 0, stream>>>(p_kl, p_rec, p_csl, out);
}

// Round 5
// 497.805 us; speedup vs baseline: 3.0091x; 1.1156x over previous
//
#include <hip/hip_runtime.h>
#include <math.h>

#define B_ 16384
#define R_ 512
#define V_ 1000
#define F_ 300
#define FP_ 320           // F padded to multiple of 32
#define L_ 512
#define H_ 512
#define LEAK_ 0.2f
#define TEMP_ 0.07f
#define DISK_ 15

#define NCSL_BLK (B_ / 4)      // 4096
#define NKL_BLK  2048
#define NREC_BLK (5 * 128)     // 640

typedef short short8 __attribute__((ext_vector_type(8)));
typedef float float4v __attribute__((ext_vector_type(4)));

__device__ __forceinline__ float waveReduceSum(float v) {
#pragma unroll
    for (int off = 32; off; off >>= 1) v += __shfl_xor(v, off);
    return v;
}

__device__ __forceinline__ short f2bf(float f) {
    unsigned u = __float_as_uint(f);
    unsigned r = (u + 0x7FFFu + ((u >> 16) & 1u)) >> 16;
    return (short)r;
}

// ---------------------------------------------------------------------------
// top-2 / bottom-15 per row. one wave per row.
// Values mapped to order-preserving uint32. Top-2: exact u64 packed keys
// (tiebreak smaller idx). Bottom-15: 32-bit packed keys (23-bit value, 9-bit
// idx) -> single shuffle+min per butterfly stage; truncation only perturbs
// loss_csl by ~0 (see round-4 notes).
// ---------------------------------------------------------------------------
__global__ __launch_bounds__(64) void topk_kernel(
    const float* __restrict__ logits, int* __restrict__ top0,
    int* __restrict__ top1, int* __restrict__ dis) {
    int b = blockIdx.x;
    int lane = threadIdx.x;
    const float* lp = logits + (size_t)b * R_;
    float4 va = *(const float4*)&lp[lane * 8];
    float4 vb = *(const float4*)&lp[lane * 8 + 4];
    float v[8] = {va.x, va.y, va.z, va.w, vb.x, vb.y, vb.z, vb.w};
    unsigned u[8];
#pragma unroll
    for (int i = 0; i < 8; ++i) {
        int f = __float_as_int(v[i]);
        u[i] = (unsigned)f ^ ((unsigned)(f >> 31) | 0x80000000u);
    }
    // ---- top-2, exact
    unsigned long long t1 = 0ull, t2 = 0ull;
#pragma unroll
    for (int i = 0; i < 8; ++i) {
        unsigned long long k =
            ((unsigned long long)u[i] << 9) | (unsigned)(511 - (lane * 8 + i));
        if (k > t1) { t2 = t1; t1 = k; }
        else if (k > t2) t2 = k;
    }
#pragma unroll
    for (int off = 32; off; off >>= 1) {
        unsigned long long o1 = __shfl_xor(t1, off);
        unsigned long long o2 = __shfl_xor(t2, off);
        unsigned long long hi = t1 > o1 ? t1 : o1;
        unsigned long long lo = t1 > o1 ? o1 : t1;
        unsigned long long m2 = t2 > o2 ? t2 : o2;
        t1 = hi;
        t2 = lo > m2 ? lo : m2;
    }
    int i0 = 511 - (int)(t1 & 511u);
    int i1 = 511 - (int)(t2 & 511u);

    // ---- bottom-15, packed 32-bit keys
    unsigned k32[8];
#pragma unroll
    for (int i = 0; i < 8; ++i) {
        int idx = lane * 8 + i;
        k32[i] = (u[i] & 0xFFFFFE00u) | (unsigned)idx;
        if (idx == i0 || idx == i1) k32[i] = 0xFFFFFFFFu;
    }
    unsigned lmin = k32[0];
#pragma unroll
    for (int i = 1; i < 8; ++i) lmin = min(lmin, k32[i]);
    int dloc[DISK_];
#pragma unroll
    for (int t = 0; t < DISK_; ++t) {
        unsigned w = lmin;
#pragma unroll
        for (int off = 32; off; off >>= 1) w = min(w, __shfl_xor(w, off));
        int idx = (int)(w & 0x1FFu);
        dloc[t] = idx;
        if ((idx >> 3) == lane) {
            k32[idx & 7] = 0xFFFFFFFFu;
            lmin = k32[0];
#pragma unroll
            for (int i = 1; i < 8; ++i) lmin = min(lmin, k32[i]);
        }
    }
    if (lane == 0) {
        top0[b] = i0; top1[b] = i1;
#pragma unroll
        for (int t = 0; t < DISK_; ++t) dis[b * DISK_ + t] = dloc[t];
    }
}

// ---------------------------------------------------------------------------
// gather d_table (fp32) + dt bf16 padded to FP_ cols. one block per relation.
// ---------------------------------------------------------------------------
__global__ __launch_bounds__(FP_) void gather_d(
    const int* __restrict__ rels32, const float* __restrict__ rel_dict,
    float* __restrict__ d_table, short* __restrict__ dt) {
    __shared__ int s_i64;
    int tid = threadIdx.x, r = blockIdx.x;
    if (tid == 0) s_i64 = 1;
    __syncthreads();
    if (rels32[2 * tid + 1] != 0) s_i64 = 0;
    __syncthreads();
    int key = s_i64 ? rels32[4 * r + 2] : rels32[2 * r + 1];
    if (tid < F_) {
        float v = rel_dict[(size_t)key * F_ + tid];
        d_table[(size_t)r * F_ + tid] = v;
        dt[(size_t)r * FP_ + tid] = f2bf(v);
    } else {
        dt[(size_t)r * FP_ + tid] = 0;
    }
}

// ---------------------------------------------------------------------------
// fused transpose of 11 weight views: fp32 W[row_off+K][N] -> bf16 Wt[Npad][Kpad]
// ---------------------------------------------------------------------------
#define NT_ 11
struct TransArgs {
    const float* W[NT_];
    short* Wt[NT_];
    int row_off[NT_];
    int K[NT_];
    int Kpad[NT_];
    int N[NT_];
    int Npad[NT_];
};
__global__ __launch_bounds__(256) void transpose_all(TransArgs ta) {
    int z = blockIdx.z;
    const float* W = ta.W[z];
    short* Wt = ta.Wt[z];
    int row_off = ta.row_off[z];
    int K = ta.K[z], Kpad = ta.Kpad[z], N = ta.N[z], Npad = ta.Npad[z];
    int k0 = blockIdx.x * 32, n0 = blockIdx.y * 32;
    if (k0 >= Kpad || n0 >= Npad) return;
    __shared__ float tile[32][33];
    int tx = threadIdx.x & 31, ty = threadIdx.x >> 5;
#pragma unroll
    for (int i = 0; i < 4; ++i) {
        int k = k0 + i * 8 + ty, n = n0 + tx;
        tile[i * 8 + ty][tx] = (k < K && n < N) ? W[(size_t)(row_off + k) * N + n] : 0.f;
    }
    __syncthreads();
#pragma unroll
    for (int i = 0; i < 4; ++i) {
        int n = n0 + i * 8 + ty, k = k0 + tx;
        if (n < Npad && k < Kpad) Wt[(size_t)n * Kpad + k] = f2bf(tile[tx][i * 8 + ty]);
    }
}

// ---------------------------------------------------------------------------
// h1 = leaky(Pcat[top0,0:512] + Pcat[top1,512:1024] + b1)  -> bf16
// ---------------------------------------------------------------------------
__global__ __launch_bounds__(256) void h1_kernel(
    const float* __restrict__ Pcat, const float* __restrict__ b1,
    const int* __restrict__ top0, const int* __restrict__ top1,
    short* __restrict__ h1b) {
    int idx = blockIdx.x * 256 + threadIdx.x;
    int b = idx >> 9, j = idx & 511;
    float v = Pcat[(size_t)top0[b] * 2048 + j] + Pcat[(size_t)top1[b] * 2048 + 512 + j] + b1[j];
    h1b[idx] = f2bf(v > 0.f ? v : LEAK_ * v);
}

// ---------------------------------------------------------------------------
// ipre = relu(Pcat[:,1536:2048] + ib1) -> bf16
// ---------------------------------------------------------------------------
__global__ __launch_bounds__(256) void ipre_kernel(
    const float* __restrict__ Pcat, const float* __restrict__ ib1,
    short* __restrict__ ipre) {
    int idx = blockIdx.x * 256 + threadIdx.x;   // R_*512 total
    int r = idx >> 9, j = idx & 511;
    float v = Pcat[(size_t)r * 2048 + 1536 + j] + ib1[j];
    ipre[idx] = f2bf(v > 0.f ? v : 0.f);
}

// ---------------------------------------------------------------------------
// z / z_ (bf16) + kl partial per block (no atomics)
// ---------------------------------------------------------------------------
__global__ __launch_bounds__(256) void zkl_kernel(
    const float* __restrict__ mu, const float* __restrict__ ls,
    const float* __restrict__ eps1, const float* __restrict__ eps2,
    short* __restrict__ zb, short* __restrict__ z_b,
    float* __restrict__ partial_kl) {
    int idx = blockIdx.x * 256 + threadIdx.x;
    int stride = gridDim.x * 256;
    float kl = 0.f;
    for (int i = idx; i < B_ * L_; i += stride) {
        float m = mu[i], l = ls[i];
        float s = __expf(l);
        zb[i]  = f2bf(m + eps1[i] * s);
        z_b[i] = f2bf(m + eps2[i] * s);
        kl += -0.5f * (1.f + 2.f * l - m * m - s * s);
    }
    __shared__ float red[4];
    kl = waveReduceSum(kl);
    int lane = threadIdx.x & 63, w = threadIdx.x >> 6;
    if (lane == 0) red[w] = kl;
    __syncthreads();
    if (threadIdx.x == 0)
        partial_kl[blockIdx.x] = red[0] + red[1] + red[2] + red[3];
}

// ---------------------------------------------------------------------------
// bf16 MFMA GEMM: C[M,*] = A[M,KK](bf16) @ Wt[N,KK](bf16, pre-transposed)
// 256 thr (4 waves), tile 128(M) x 64(N), BK=32, double-buffered LDS.
//  EPI 0: fp32 store  acc + bias                       (unused now)
//  EPI 1: bf16 store  leaky(acc + bias + table[rowsel])(h3)
//  EPI 2: bf16 store  relu(acc + bias)                 (t)
//  EPI 3: partial[blk] = sum (tanh(acc+bias)-table[rowsel])^2   (recon)
//  EPI 4: fp32 store  relu(acc + bias)                 (z_p, ipost)
//  EPI 5: fp32 store  acc (no bias)                    (Pcat)
//  EPI 6: fp32 dual-store: cols<512 -> C (+bias), cols>=512 -> C2 (+bias2)  (mu|ls)
// ---------------------------------------------------------------------------
template <int EPI, int KK>
__global__ __launch_bounds__(256) void gemm_mfma(
    const short* __restrict__ A, const short* __restrict__ Wt,
    void* __restrict__ C, int ldc, const float* __restrict__ bias,
    const float* __restrict__ table, int tld,
    const int* __restrict__ rowsel, float* __restrict__ lossp, int N,
    float* __restrict__ C2, const float* __restrict__ bias2) {
    __shared__ __align__(16) short Asl[2][128][40];
    __shared__ __align__(16) short Bsl[2][64][40];
    __shared__ float sred[4];
    int tid = threadIdx.x;
    int lane = tid & 63, wv = tid >> 6;
    int lm = lane & 15, q = lane >> 4;
    int row0 = blockIdx.y * 128;
    int col0 = blockIdx.x * 64;

    float4v acc[2][4];
#pragma unroll
    for (int i = 0; i < 2; ++i)
#pragma unroll
        for (int j = 0; j < 4; ++j) acc[i][j] = {0.f, 0.f, 0.f, 0.f};

    uint4 aReg[2], bReg;
    int ar0 = tid >> 2, ak = (tid & 3) * 8;
    int ar1 = (tid + 256) >> 2;
    int br = tid >> 2, bk = (tid & 3) * 8;

    auto loadG = [&](int k0) {
        aReg[0] = *(const uint4*)&A[(size_t)(row0 + ar0) * KK + k0 + ak];
        aReg[1] = *(const uint4*)&A[(size_t)(row0 + ar1) * KK + k0 + ak];
        bReg    = *(const uint4*)&Wt[(size_t)(col0 + br) * KK + k0 + bk];
    };
    auto storeL = [&](int p) {
        *(uint4*)&Asl[p][ar0][ak] = aReg[0];
        *(uint4*)&Asl[p][ar1][ak] = aReg[1];
        *(uint4*)&Bsl[p][br][bk]  = bReg;
    };

    int p = 0;
    loadG(0);
    storeL(0);
    for (int k0 = 0; k0 < KK; k0 += 32) {
        __syncthreads();
        bool more = (k0 + 32) < KK;
        if (more) loadG(k0 + 32);
        short8 af[2], bfr[4];
#pragma unroll
        for (int mt = 0; mt < 2; ++mt)
            af[mt] = *(const short8*)&Asl[p][wv * 32 + mt * 16 + lm][q * 8];
#pragma unroll
        for (int nt = 0; nt < 4; ++nt)
            bfr[nt] = *(const short8*)&Bsl[p][nt * 16 + lm][q * 8];
#pragma unroll
        for (int mt = 0; mt < 2; ++mt)
#pragma unroll
            for (int nt = 0; nt < 4; ++nt)
                acc[mt][nt] = __builtin_amdgcn_mfma_f32_16x16x32_bf16(
                    af[mt], bfr[nt], acc[mt][nt], 0, 0, 0);
        if (more) { p ^= 1; storeL(p); }
    }

    if (EPI == 3) {
        float lsum = 0.f;
#pragma unroll
        for (int mt = 0; mt < 2; ++mt) {
#pragma unroll
            for (int r = 0; r < 4; ++r) {
                int grow = row0 + wv * 32 + mt * 16 + q * 4 + r;
                int trow = rowsel[grow];
#pragma unroll
                for (int nt = 0; nt < 4; ++nt) {
                    int gcol = col0 + nt * 16 + lm;
                    if (gcol < N) {
                        float v = tanhf(acc[mt][nt][r] + bias[gcol]);
                        float d = v - table[(size_t)trow * tld + gcol];
                        lsum += d * d;
                    }
                }
            }
        }
        lsum = waveReduceSum(lsum);
        if (lane == 0) sred[wv] = lsum;
        __syncthreads();
        if (tid == 0)
            lossp[blockIdx.y * gridDim.x + blockIdx.x] =
                sred[0] + sred[1] + sred[2] + sred[3];
    } else {
#pragma unroll
        for (int mt = 0; mt < 2; ++mt) {
#pragma unroll
            for (int r = 0; r < 4; ++r) {
                int grow = row0 + wv * 32 + mt * 16 + q * 4 + r;
                int trow = (EPI == 1) ? rowsel[grow] : 0;
#pragma unroll
                for (int nt = 0; nt < 4; ++nt) {
                    int gcol = col0 + nt * 16 + lm;
                    float v = acc[mt][nt][r];
                    if (EPI == 6) {
                        if (gcol < 512)
                            ((float*)C)[(size_t)grow * 512 + gcol] = v + bias[gcol];
                        else
                            C2[(size_t)grow * 512 + gcol - 512] = v + bias2[gcol - 512];
                        continue;
                    }
                    if (EPI != 5) v += bias[gcol];
                    if (EPI == 1) {
                        v += table[(size_t)trow * tld + gcol];
                        v = v > 0.f ? v : LEAK_ * v;
                    }
                    if (EPI == 2 || EPI == 4) v = v > 0.f ? v : 0.f;
                    if (EPI == 0 || EPI == 4 || EPI == 5)
                        ((float*)C)[(size_t)grow * ldc + gcol] = v;
                    else
                        ((short*)C)[(size_t)grow * ldc + gcol] = f2bf(v);
                }
            }
        }
    }
}

// ---------------------------------------------------------------------------
// contrastive loss: one wave per row, per-block partial (no atomics)
// ---------------------------------------------------------------------------
__global__ __launch_bounds__(256) void csl_kernel(
    const float* __restrict__ zp, const float* __restrict__ ipost,
    const int* __restrict__ top0, const int* __restrict__ dis,
    float* __restrict__ partial_csl) {
    __shared__ float sred[4];
    int w = threadIdx.x >> 6, lane = threadIdx.x & 63;
    int b = blockIdx.x * 4 + w;
    const float* zr = zp + (size_t)b * 512;
    float z[8];
#pragma unroll
    for (int i = 0; i < 8; ++i) z[i] = zr[i * 64 + lane];
    int cand[16];
    cand[0] = top0[b];
#pragma unroll
    for (int n = 0; n < DISK_; ++n) cand[n + 1] = dis[b * DISK_ + n];
    float s[16];
#pragma unroll
    for (int c = 0; c < 16; ++c) {
        const float* ip = ipost + (size_t)cand[c] * 512;
        float a = 0.f;
#pragma unroll
        for (int i = 0; i < 8; ++i) a += z[i] * ip[i * 64 + lane];
        s[c] = a;
    }
#pragma unroll
    for (int off = 32; off; off >>= 1) {
        float o[16];
#pragma unroll
        for (int c = 0; c < 16; ++c) o[c] = __shfl_xor(s[c], off);
#pragma unroll
        for (int c = 0; c < 16; ++c) s[c] += o[c];
    }
    if (lane == 0) {
        float m = s[0];
#pragma unroll
        for (int c = 1; c < 16; ++c) m = fmaxf(m, s[c]);
        float se = 0.f;
#pragma unroll
        for (int c = 0; c < 16; ++c) se += __expf((s[c] - m) / TEMP_);
        sred[w] = -((s[0] - m) / TEMP_ - __logf(se));
    }
    __syncthreads();
    if (threadIdx.x == 0)
        partial_csl[blockIdx.x] = sred[0] + sred[1] + sred[2] + sred[3];
}

// ---------------------------------------------------------------------------
// finalize: out[0] = kl + recon; out[1] = csl; out[2..513] = 0 (z_rel row 0)
// ---------------------------------------------------------------------------
__global__ __launch_bounds__(256) void finalize_kernel(
    const float* __restrict__ pkl, const float* __restrict__ prec,
    const float* __restrict__ pcsl, float* __restrict__ out) {
    __shared__ float red[4][2];
    int tid = threadIdx.x;
    out[2 + tid] = 0.f;
    out[2 + 256 + tid] = 0.f;
    float a0 = 0.f, a1 = 0.f;
    for (int i = tid; i < NKL_BLK; i += 256) a0 += pkl[i];
    for (int i = tid; i < NREC_BLK; i += 256) a0 += prec[i];
    for (int i = tid; i < NCSL_BLK; i += 256) a1 += pcsl[i];
    a0 = waveReduceSum(a0);
    a1 = waveReduceSum(a1);
    int lane = tid & 63, w = tid >> 6;
    if (lane == 0) { red[w][0] = a0; red[w][1] = a1; }
    __syncthreads();
    if (tid == 0) out[0] = red[0][0] + red[1][0] + red[2][0] + red[3][0];
    if (tid == 1) out[1] = red[0][1] + red[1][1] + red[2][1] + red[3][1];
}

// ---------------------------------------------------------------------------
extern "C" void kernel_launch(void* const* d_in, const int* in_sizes, int n_in,
                              void* d_out, int out_size, void* d_ws, size_t ws_size,
                              hipStream_t stream) {
    const float* logits  = (const float*)d_in[0];
    const int*   rels    = (const int*)d_in[1];
    const float* rel_dict= (const float*)d_in[2];
    const float* eps1    = (const float*)d_in[3];
    const float* eps2    = (const float*)d_in[4];
    const float* W1  = (const float*)d_in[5];
    const float* b1  = (const float*)d_in[6];
    const float* Wmu = (const float*)d_in[7];
    const float* bmu = (const float*)d_in[8];
    const float* Wls = (const float*)d_in[9];
    const float* bls = (const float*)d_in[10];
    const float* W3  = (const float*)d_in[11];
    const float* b3  = (const float*)d_in[12];
    const float* W4  = (const float*)d_in[13];
    const float* b4  = (const float*)d_in[14];
    const float* iW1 = (const float*)d_in[15];
    const float* ib1 = (const float*)d_in[16];
    const float* iW2 = (const float*)d_in[17];
    const float* ib2 = (const float*)d_in[18];
    const float* zW1 = (const float*)d_in[19];
    const float* zb1 = (const float*)d_in[20];
    const float* zW2 = (const float*)d_in[21];
    const float* zb2 = (const float*)d_in[22];
    float* out = (float*)d_out;

    char* wsp = (char*)d_ws;
    size_t off = 0;
    auto alloc = [&](size_t bytes) { void* p = wsp + off; off += (bytes + 255) & ~(size_t)255; return p; };
    int*   top0    = (int*)alloc(B_ * 4);
    int*   top1    = (int*)alloc(B_ * 4);
    int*   dis     = (int*)alloc(B_ * DISK_ * 4);
    float* d_table = (float*)alloc((size_t)R_ * F_ * 4);
    short* dt      = (short*)alloc((size_t)R_ * FP_ * 2);
    short* Wcat_t  = (short*)alloc((size_t)2048 * FP_ * 2);
    float* Pcat    = (float*)alloc((size_t)R_ * 2048 * 4);
    short* ipre    = (short*)alloc((size_t)R_ * H_ * 2);
    float* ipost   = (float*)alloc((size_t)R_ * H_ * 4);
    short* Wt_muls = (short*)alloc((size_t)1024 * 512 * 2);
    short* Wt_3    = (short*)alloc((size_t)512 * 512 * 2);
    short* Wt_z1   = (short*)alloc((size_t)512 * 512 * 2);
    short* Wt_z2   = (short*)alloc((size_t)512 * 512 * 2);
    short* Wt_4    = (short*)alloc((size_t)320 * 512 * 2);
    short* Wt_i2   = (short*)alloc((size_t)512 * 512 * 2);
    float* buf1    = (float*)alloc((size_t)B_ * H_ * 4);   // mu
    float* buf2    = (float*)alloc((size_t)B_ * H_ * 4);   // ls
    short* bfA     = (short*)alloc((size_t)B_ * H_ * 2);   // h1 -> h3
    short* bfB     = (short*)alloc((size_t)B_ * H_ * 2);   // z  -> t
    short* bfC     = (short*)alloc((size_t)B_ * H_ * 2);   // z_
    float* p_csl   = (float*)alloc(NCSL_BLK * 4);
    float* p_kl    = (float*)alloc(NKL_BLK * 4);
    float* p_rec   = (float*)alloc(NREC_BLK * 4);

    topk_kernel<<<B_, 64, 0, stream>>>(logits, top0, top1, dis);
    gather_d<<<R_, FP_, 0, stream>>>(rels, rel_dict, d_table, dt);

    TransArgs ta;
    auto set = [&](int i, const float* W, short* Wt, int ro, int K, int Kp, int N, int Np) {
        ta.W[i] = W; ta.Wt[i] = Wt; ta.row_off[i] = ro; ta.K[i] = K;
        ta.Kpad[i] = Kp; ta.N[i] = N; ta.Npad[i] = Np;
    };
    set(0, Wmu, Wt_muls,             0, 512, 512, 512, 512);
    set(1, Wls, Wt_muls + 512 * 512, 0, 512, 512, 512, 512);
    set(2, W3,  Wt_3,  0, 512, 512, 512, 512);
    set(3, zW1, Wt_z1, 0, 512, 512, 512, 512);
    set(4, zW2, Wt_z2, 0, 512, 512, 512, 512);
    set(5, W4,  Wt_4,  0, 512, 512, 300, 320);
    set(6, W1,  Wcat_t,                 0,   F_, FP_, 512, 512);   // P1 weights
    set(7, W1,  Wcat_t + 512 * FP_,     F_,  F_, FP_, 512, 512);   // P2 weights
    set(8, W3,  Wcat_t + 1024 * FP_,    L_,  F_, FP_, 512, 512);   // P3 weights
    set(9, iW1, Wcat_t + 1536 * FP_,    0,   F_, FP_, 512, 512);   // ipre weights
    set(10, iW2, Wt_i2, 0, 512, 512, 512, 512);
    transpose_all<<<dim3(16, 16, NT_), 256, 0, stream>>>(ta);

    // Pcat[512][2048] = dt @ Wcat  (no bias)
    gemm_mfma<5, FP_><<<dim3(32, 4), 256, 0, stream>>>(
        dt, Wcat_t, Pcat, 2048, nullptr, nullptr, 0, nullptr, nullptr, 2048, nullptr, nullptr);
    ipre_kernel<<<R_ * H_ / 256, 256, 0, stream>>>(Pcat, ib1, ipre);
    // ipost = relu(ipre @ iW2 + ib2)  fp32
    gemm_mfma<4, 512><<<dim3(8, 4), 256, 0, stream>>>(
        ipre, Wt_i2, ipost, 512, ib2, nullptr, 0, nullptr, nullptr, 512, nullptr, nullptr);

    h1_kernel<<<B_ * H_ / 256, 256, 0, stream>>>(Pcat, b1, top0, top1, bfA);

    dim3 g16(16, 128), g8(8, 128), g5(5, 128);
    // mu | ls fused (N=1024)
    gemm_mfma<6, 512><<<g16, 256, 0, stream>>>(bfA, Wt_muls, buf1, 512, bmu, nullptr, 0, nullptr, nullptr, 1024, buf2, bls);
    zkl_kernel<<<NKL_BLK, 256, 0, stream>>>(buf1, buf2, eps1, eps2, bfB, bfC, p_kl);
    // h3 = leaky(z @ W3[:512] + Pcat[top1,1024:1536] + b3)
    gemm_mfma<1, 512><<<g8, 256, 0, stream>>>(bfB, Wt_3, bfA, 512, b3, Pcat + 1024, 2048, top1, nullptr, 512, nullptr, nullptr);
    gemm_mfma<3, 512><<<g5, 256, 0, stream>>>(bfA, Wt_4, nullptr, 0, b4, d_table, F_, top0, p_rec, 300, nullptr, nullptr);
    gemm_mfma<2, 512><<<g8, 256, 0, stream>>>(bfC, Wt_z1, bfB, 512, zb1, nullptr, 0, nullptr, nullptr, 512, nullptr, nullptr);
    gemm_mfma<4, 512><<<g8, 256, 0, stream>>>(bfB, Wt_z2, out + 2 + L_, 512, zb2, nullptr, 0, nullptr, nullptr, 512, nullptr, nullptr);
    csl_kernel<<<NCSL_BLK, 256, 0, stream>>>(out + 2 + L_, ipost, top0, dis, p_csl);
    finalize_kernel<<<1, 256, 0, stream>>>(p_kl, p_rec, p_csl, out);
}

// Round 6
// 482.237 us; speedup vs baseline: 3.1062x; 1.0323x over previous
//
#include <hip/hip_runtime.h>
#include <math.h>

#define B_ 16384
#define R_ 512
#define V_ 1000
#define F_ 300
#define FP_ 320           // F padded to multiple of 32
#define L_ 512
#define H_ 512
#define LEAK_ 0.2f
#define TEMP_ 0.07f
#define DISK_ 15

#define NCSL_BLK (B_ / 4)      // 4096
#define NKL_BLK  2048          // fused mu|ls GEMM grid 16x128
#define NREC_BLK (5 * 128)     // 640

typedef short short8 __attribute__((ext_vector_type(8)));
typedef float float4v __attribute__((ext_vector_type(4)));

__device__ __forceinline__ float waveReduceSum(float v) {
#pragma unroll
    for (int off = 32; off; off >>= 1) v += __shfl_xor(v, off);
    return v;
}

__device__ __forceinline__ short f2bf(float f) {
    unsigned u = __float_as_uint(f);
    unsigned r = (u + 0x7FFFu + ((u >> 16) & 1u)) >> 16;
    return (short)r;
}

// ---------------------------------------------------------------------------
// top-2 / bottom-15 per row. one wave per row. (see round-4 notes)
// ---------------------------------------------------------------------------
__global__ __launch_bounds__(64) void topk_kernel(
    const float* __restrict__ logits, int* __restrict__ top0,
    int* __restrict__ top1, int* __restrict__ dis) {
    int b = blockIdx.x;
    int lane = threadIdx.x;
    const float* lp = logits + (size_t)b * R_;
    float4 va = *(const float4*)&lp[lane * 8];
    float4 vb = *(const float4*)&lp[lane * 8 + 4];
    float v[8] = {va.x, va.y, va.z, va.w, vb.x, vb.y, vb.z, vb.w};
    unsigned u[8];
#pragma unroll
    for (int i = 0; i < 8; ++i) {
        int f = __float_as_int(v[i]);
        u[i] = (unsigned)f ^ ((unsigned)(f >> 31) | 0x80000000u);
    }
    // ---- top-2, exact
    unsigned long long t1 = 0ull, t2 = 0ull;
#pragma unroll
    for (int i = 0; i < 8; ++i) {
        unsigned long long k =
            ((unsigned long long)u[i] << 9) | (unsigned)(511 - (lane * 8 + i));
        if (k > t1) { t2 = t1; t1 = k; }
        else if (k > t2) t2 = k;
    }
#pragma unroll
    for (int off = 32; off; off >>= 1) {
        unsigned long long o1 = __shfl_xor(t1, off);
        unsigned long long o2 = __shfl_xor(t2, off);
        unsigned long long hi = t1 > o1 ? t1 : o1;
        unsigned long long lo = t1 > o1 ? o1 : t1;
        unsigned long long m2 = t2 > o2 ? t2 : o2;
        t1 = hi;
        t2 = lo > m2 ? lo : m2;
    }
    int i0 = 511 - (int)(t1 & 511u);
    int i1 = 511 - (int)(t2 & 511u);

    // ---- bottom-15, packed 32-bit keys
    unsigned k32[8];
#pragma unroll
    for (int i = 0; i < 8; ++i) {
        int idx = lane * 8 + i;
        k32[i] = (u[i] & 0xFFFFFE00u) | (unsigned)idx;
        if (idx == i0 || idx == i1) k32[i] = 0xFFFFFFFFu;
    }
    unsigned lmin = k32[0];
#pragma unroll
    for (int i = 1; i < 8; ++i) lmin = min(lmin, k32[i]);
    int dloc[DISK_];
#pragma unroll
    for (int t = 0; t < DISK_; ++t) {
        unsigned w = lmin;
#pragma unroll
        for (int off = 32; off; off >>= 1) w = min(w, __shfl_xor(w, off));
        int idx = (int)(w & 0x1FFu);
        dloc[t] = idx;
        if ((idx >> 3) == lane) {
            k32[idx & 7] = 0xFFFFFFFFu;
            lmin = k32[0];
#pragma unroll
            for (int i = 1; i < 8; ++i) lmin = min(lmin, k32[i]);
        }
    }
    if (lane == 0) {
        top0[b] = i0; top1[b] = i1;
#pragma unroll
        for (int t = 0; t < DISK_; ++t) dis[b * DISK_ + t] = dloc[t];
    }
}

// ---------------------------------------------------------------------------
// gather d_table (fp32) + dt bf16 padded to FP_ cols. one block per relation.
// ---------------------------------------------------------------------------
__global__ __launch_bounds__(FP_) void gather_d(
    const int* __restrict__ rels32, const float* __restrict__ rel_dict,
    float* __restrict__ d_table, short* __restrict__ dt) {
    __shared__ int s_i64;
    int tid = threadIdx.x, r = blockIdx.x;
    if (tid == 0) s_i64 = 1;
    __syncthreads();
    if (rels32[2 * tid + 1] != 0) s_i64 = 0;
    __syncthreads();
    int key = s_i64 ? rels32[4 * r + 2] : rels32[2 * r + 1];
    if (tid < F_) {
        float v = rel_dict[(size_t)key * F_ + tid];
        d_table[(size_t)r * F_ + tid] = v;
        dt[(size_t)r * FP_ + tid] = f2bf(v);
    } else {
        dt[(size_t)r * FP_ + tid] = 0;
    }
}

// ---------------------------------------------------------------------------
// fused transpose of 11 weight views: fp32 W[row_off+K][N] -> bf16 Wt[*][Kpad]
// ilv >= 0: interleaved output row = ilv + 64*(n>>5) + (n&31)  (mu|ls pairing)
// ---------------------------------------------------------------------------
#define NT_ 11
struct TransArgs {
    const float* W[NT_];
    short* Wt[NT_];
    int row_off[NT_];
    int K[NT_];
    int Kpad[NT_];
    int N[NT_];
    int Npad[NT_];
    int ilv[NT_];
};
__global__ __launch_bounds__(256) void transpose_all(TransArgs ta) {
    int z = blockIdx.z;
    const float* W = ta.W[z];
    short* Wt = ta.Wt[z];
    int row_off = ta.row_off[z];
    int K = ta.K[z], Kpad = ta.Kpad[z], N = ta.N[z], Npad = ta.Npad[z];
    int ilv = ta.ilv[z];
    int k0 = blockIdx.x * 32, n0 = blockIdx.y * 32;
    if (k0 >= Kpad || n0 >= Npad) return;
    __shared__ float tile[32][33];
    int tx = threadIdx.x & 31, ty = threadIdx.x >> 5;
#pragma unroll
    for (int i = 0; i < 4; ++i) {
        int k = k0 + i * 8 + ty, n = n0 + tx;
        tile[i * 8 + ty][tx] = (k < K && n < N) ? W[(size_t)(row_off + k) * N + n] : 0.f;
    }
    __syncthreads();
#pragma unroll
    for (int i = 0; i < 4; ++i) {
        int n = n0 + i * 8 + ty, k = k0 + tx;
        if (n < Npad && k < Kpad) {
            int orow = (ilv >= 0) ? (ilv + 64 * (n >> 5) + (n & 31)) : n;
            Wt[(size_t)orow * Kpad + k] = f2bf(tile[tx][i * 8 + ty]);
        }
    }
}

// ---------------------------------------------------------------------------
// h1 = leaky(Pcat[top0,0:512] + Pcat[top1,512:1024] + b1)  -> bf16
// ---------------------------------------------------------------------------
__global__ __launch_bounds__(256) void h1_kernel(
    const float* __restrict__ Pcat, const float* __restrict__ b1,
    const int* __restrict__ top0, const int* __restrict__ top1,
    short* __restrict__ h1b) {
    int idx = blockIdx.x * 256 + threadIdx.x;
    int b = idx >> 9, j = idx & 511;
    float v = Pcat[(size_t)top0[b] * 2048 + j] + Pcat[(size_t)top1[b] * 2048 + 512 + j] + b1[j];
    h1b[idx] = f2bf(v > 0.f ? v : LEAK_ * v);
}

// ---------------------------------------------------------------------------
// ipre = relu(Pcat[:,1536:2048] + ib1) -> bf16
// ---------------------------------------------------------------------------
__global__ __launch_bounds__(256) void ipre_kernel(
    const float* __restrict__ Pcat, const float* __restrict__ ib1,
    short* __restrict__ ipre) {
    int idx = blockIdx.x * 256 + threadIdx.x;   // R_*512 total
    int r = idx >> 9, j = idx & 511;
    float v = Pcat[(size_t)r * 2048 + 1536 + j] + ib1[j];
    ipre[idx] = f2bf(v > 0.f ? v : 0.f);
}

// ---------------------------------------------------------------------------
// bf16 MFMA GEMM: C[M,*] = A[M,KK](bf16) @ Wt[N,KK](bf16, pre-transposed)
// 256 thr (4 waves), tile 128(M) x 64(N), BK=32, double-buffered LDS.
// SWZ: XCD-locality swizzle (requires gridDim.y==128): l=flat id,
//      by=l&127, bx=l>>7 -> all 16/8 blocks of a row-stripe on one XCD.
//  EPI 1: bf16 store  leaky(acc + bias + table[rowsel])(h3)
//  EPI 2: bf16 store  relu(acc + bias)                 (t)
//  EPI 3: partial[l] = sum (tanh(acc+bias)-table[rowsel])^2   (recon)
//  EPI 4: fp32 store  relu(acc + bias)                 (z_p, ipost)
//  EPI 5: fp32 store  acc (no bias)                    (Pcat)
//  EPI 7: fused mu|ls -> z,z_ bf16 + kl partial. acc cols [0,32)=mu,
//         [32,64)=ls for j = 32*bx + (nt&1)*16+lm (interleaved Wt).
// ---------------------------------------------------------------------------
template <int EPI, int KK, bool SWZ>
__global__ __launch_bounds__(256) void gemm_mfma(
    const short* __restrict__ A, const short* __restrict__ Wt,
    void* __restrict__ C, int ldc, const float* __restrict__ bias,
    const float* __restrict__ table, int tld,
    const int* __restrict__ rowsel, float* __restrict__ lossp, int N,
    void* __restrict__ C2, const float* __restrict__ bias2,
    const float* __restrict__ eps1, const float* __restrict__ eps2) {
    __shared__ __align__(16) short Asl[2][128][40];
    __shared__ __align__(16) short Bsl[2][64][40];
    __shared__ float sred[4];
    int tid = threadIdx.x;
    int lane = tid & 63, wv = tid >> 6;
    int lm = lane & 15, q = lane >> 4;
    int l = blockIdx.x + gridDim.x * blockIdx.y;
    int bx = SWZ ? (l >> 7) : blockIdx.x;
    int by = SWZ ? (l & 127) : blockIdx.y;
    int row0 = by * 128;
    int col0 = bx * 64;

    float4v acc[2][4];
#pragma unroll
    for (int i = 0; i < 2; ++i)
#pragma unroll
        for (int j = 0; j < 4; ++j) acc[i][j] = {0.f, 0.f, 0.f, 0.f};

    uint4 aReg[2], bReg;
    int ar0 = tid >> 2, ak = (tid & 3) * 8;
    int ar1 = (tid + 256) >> 2;
    int br = tid >> 2, bk = (tid & 3) * 8;

    auto loadG = [&](int k0) {
        aReg[0] = *(const uint4*)&A[(size_t)(row0 + ar0) * KK + k0 + ak];
        aReg[1] = *(const uint4*)&A[(size_t)(row0 + ar1) * KK + k0 + ak];
        bReg    = *(const uint4*)&Wt[(size_t)(col0 + br) * KK + k0 + bk];
    };
    auto storeL = [&](int p) {
        *(uint4*)&Asl[p][ar0][ak] = aReg[0];
        *(uint4*)&Asl[p][ar1][ak] = aReg[1];
        *(uint4*)&Bsl[p][br][bk]  = bReg;
    };

    int p = 0;
    loadG(0);
    storeL(0);
    for (int k0 = 0; k0 < KK; k0 += 32) {
        __syncthreads();
        bool more = (k0 + 32) < KK;
        if (more) loadG(k0 + 32);
        short8 af[2], bfr[4];
#pragma unroll
        for (int mt = 0; mt < 2; ++mt)
            af[mt] = *(const short8*)&Asl[p][wv * 32 + mt * 16 + lm][q * 8];
#pragma unroll
        for (int nt = 0; nt < 4; ++nt)
            bfr[nt] = *(const short8*)&Bsl[p][nt * 16 + lm][q * 8];
#pragma unroll
        for (int mt = 0; mt < 2; ++mt)
#pragma unroll
            for (int nt = 0; nt < 4; ++nt)
                acc[mt][nt] = __builtin_amdgcn_mfma_f32_16x16x32_bf16(
                    af[mt], bfr[nt], acc[mt][nt], 0, 0, 0);
        if (more) { p ^= 1; storeL(p); }
    }

    if (EPI == 3) {
        float lsum = 0.f;
#pragma unroll
        for (int mt = 0; mt < 2; ++mt) {
#pragma unroll
            for (int r = 0; r < 4; ++r) {
                int grow = row0 + wv * 32 + mt * 16 + q * 4 + r;
                int trow = rowsel[grow];
#pragma unroll
                for (int nt = 0; nt < 4; ++nt) {
                    int gcol = col0 + nt * 16 + lm;
                    if (gcol < N) {
                        float v = tanhf(acc[mt][nt][r] + bias[gcol]);
                        float d = v - table[(size_t)trow * tld + gcol];
                        lsum += d * d;
                    }
                }
            }
        }
        lsum = waveReduceSum(lsum);
        if (lane == 0) sred[wv] = lsum;
        __syncthreads();
        if (tid == 0) lossp[l] = sred[0] + sred[1] + sred[2] + sred[3];
    } else if (EPI == 7) {
        float kl = 0.f;
#pragma unroll
        for (int mt = 0; mt < 2; ++mt) {
#pragma unroll
            for (int r = 0; r < 4; ++r) {
                int grow = row0 + wv * 32 + mt * 16 + q * 4 + r;
#pragma unroll
                for (int jj = 0; jj < 2; ++jj) {
                    int j = (col0 >> 1) + jj * 16 + lm;
                    float m = acc[mt][jj][r] + bias[j];
                    float lsv = acc[mt][jj + 2][r] + bias2[j];
                    float s = __expf(lsv);
                    size_t ix = (size_t)grow * 512 + j;
                    ((short*)C)[ix]  = f2bf(m + eps1[ix] * s);
                    ((short*)C2)[ix] = f2bf(m + eps2[ix] * s);
                    kl += -0.5f * (1.f + 2.f * lsv - m * m - s * s);
                }
            }
        }
        kl = waveReduceSum(kl);
        if (lane == 0) sred[wv] = kl;
        __syncthreads();
        if (tid == 0) lossp[l] = sred[0] + sred[1] + sred[2] + sred[3];
    } else {
#pragma unroll
        for (int mt = 0; mt < 2; ++mt) {
#pragma unroll
            for (int r = 0; r < 4; ++r) {
                int grow = row0 + wv * 32 + mt * 16 + q * 4 + r;
                int trow = (EPI == 1) ? rowsel[grow] : 0;
#pragma unroll
                for (int nt = 0; nt < 4; ++nt) {
                    int gcol = col0 + nt * 16 + lm;
                    float v = acc[mt][nt][r];
                    if (EPI != 5) v += bias[gcol];
                    if (EPI == 1) {
                        v += table[(size_t)trow * tld + gcol];
                        v = v > 0.f ? v : LEAK_ * v;
                    }
                    if (EPI == 2 || EPI == 4) v = v > 0.f ? v : 0.f;
                    if (EPI == 4 || EPI == 5)
                        ((float*)C)[(size_t)grow * ldc + gcol] = v;
                    else
                        ((short*)C)[(size_t)grow * ldc + gcol] = f2bf(v);
                }
            }
        }
    }
}

// ---------------------------------------------------------------------------
// contrastive loss: one wave per row, per-block partial (no atomics)
// ---------------------------------------------------------------------------
__global__ __launch_bounds__(256) void csl_kernel(
    const float* __restrict__ zp, const float* __restrict__ ipost,
    const int* __restrict__ top0, const int* __restrict__ dis,
    float* __restrict__ partial_csl) {
    __shared__ float sred[4];
    int w = threadIdx.x >> 6, lane = threadIdx.x & 63;
    int b = blockIdx.x * 4 + w;
    const float* zr = zp + (size_t)b * 512;
    float z[8];
#pragma unroll
    for (int i = 0; i < 8; ++i) z[i] = zr[i * 64 + lane];
    int cand[16];
    cand[0] = top0[b];
#pragma unroll
    for (int n = 0; n < DISK_; ++n) cand[n + 1] = dis[b * DISK_ + n];
    float s[16];
#pragma unroll
    for (int c = 0; c < 16; ++c) {
        const float* ip = ipost + (size_t)cand[c] * 512;
        float a = 0.f;
#pragma unroll
        for (int i = 0; i < 8; ++i) a += z[i] * ip[i * 64 + lane];
        s[c] = a;
    }
#pragma unroll
    for (int off = 32; off; off >>= 1) {
        float o[16];
#pragma unroll
        for (int c = 0; c < 16; ++c) o[c] = __shfl_xor(s[c], off);
#pragma unroll
        for (int c = 0; c < 16; ++c) s[c] += o[c];
    }
    if (lane == 0) {
        float m = s[0];
#pragma unroll
        for (int c = 1; c < 16; ++c) m = fmaxf(m, s[c]);
        float se = 0.f;
#pragma unroll
        for (int c = 0; c < 16; ++c) se += __expf((s[c] - m) / TEMP_);
        sred[w] = -((s[0] - m) / TEMP_ - __logf(se));
    }
    __syncthreads();
    if (threadIdx.x == 0)
        partial_csl[blockIdx.x] = sred[0] + sred[1] + sred[2] + sred[3];
}

// ---------------------------------------------------------------------------
// finalize: out[0] = kl + recon; out[1] = csl; out[2..513] = 0 (z_rel row 0)
// ---------------------------------------------------------------------------
__global__ __launch_bounds__(256) void finalize_kernel(
    const float* __restrict__ pkl, const float* __restrict__ prec,
    const float* __restrict__ pcsl, float* __restrict__ out) {
    __shared__ float red[4][2];
    int tid = threadIdx.x;
    out[2 + tid] = 0.f;
    out[2 + 256 + tid] = 0.f;
    float a0 = 0.f, a1 = 0.f;
    for (int i = tid; i < NKL_BLK; i += 256) a0 += pkl[i];
    for (int i = tid; i < NREC_BLK; i += 256) a0 += prec[i];
    for (int i = tid; i < NCSL_BLK; i += 256) a1 += pcsl[i];
    a0 = waveReduceSum(a0);
    a1 = waveReduceSum(a1);
    int lane = tid & 63, w = tid >> 6;
    if (lane == 0) { red[w][0] = a0; red[w][1] = a1; }
    __syncthreads();
    if (tid == 0) out[0] = red[0][0] + red[1][0] + red[2][0] + red[3][0];
    if (tid == 1) out[1] = red[0][1] + red[1][1] + red[2][1] + red[3][1];
}

// ---------------------------------------------------------------------------
extern "C" void kernel_launch(void* const* d_in, const int* in_sizes, int n_in,
                              void* d_out, int out_size, void* d_ws, size_t ws_size,
                              hipStream_t stream) {
    const float* logits  = (const float*)d_in[0];
    const int*   rels    = (const int*)d_in[1];
    const float* rel_dict= (const float*)d_in[2];
    const float* eps1    = (const float*)d_in[3];
    const float* eps2    = (const float*)d_in[4];
    const float* W1  = (const float*)d_in[5];
    const float* b1  = (const float*)d_in[6];
    const float* Wmu = (const float*)d_in[7];
    const float* bmu = (const float*)d_in[8];
    const float* Wls = (const float*)d_in[9];
    const float* bls = (const float*)d_in[10];
    const float* W3  = (const float*)d_in[11];
    const float* b3  = (const float*)d_in[12];
    const float* W4  = (const float*)d_in[13];
    const float* b4  = (const float*)d_in[14];
    const float* iW1 = (const float*)d_in[15];
    const float* ib1 = (const float*)d_in[16];
    const float* iW2 = (const float*)d_in[17];
    const float* ib2 = (const float*)d_in[18];
    const float* zW1 = (const float*)d_in[19];
    const float* zb1 = (const float*)d_in[20];
    const float* zW2 = (const float*)d_in[21];
    const float* zb2 = (const float*)d_in[22];
    float* out = (float*)d_out;

    char* wsp = (char*)d_ws;
    size_t off = 0;
    auto alloc = [&](size_t bytes) { void* p = wsp + off; off += (bytes + 255) & ~(size_t)255; return p; };
    int*   top0    = (int*)alloc(B_ * 4);
    int*   top1    = (int*)alloc(B_ * 4);
    int*   dis     = (int*)alloc(B_ * DISK_ * 4);
    float* d_table = (float*)alloc((size_t)R_ * F_ * 4);
    short* dt      = (short*)alloc((size_t)R_ * FP_ * 2);
    short* Wcat_t  = (short*)alloc((size_t)2048 * FP_ * 2);
    float* Pcat    = (float*)alloc((size_t)R_ * 2048 * 4);
    short* ipre    = (short*)alloc((size_t)R_ * H_ * 2);
    float* ipost   = (float*)alloc((size_t)R_ * H_ * 4);
    short* Wt_muls = (short*)alloc((size_t)1024 * 512 * 2);
    short* Wt_3    = (short*)alloc((size_t)512 * 512 * 2);
    short* Wt_z1   = (short*)alloc((size_t)512 * 512 * 2);
    short* Wt_z2   = (short*)alloc((size_t)512 * 512 * 2);
    short* Wt_4    = (short*)alloc((size_t)320 * 512 * 2);
    short* Wt_i2   = (short*)alloc((size_t)512 * 512 * 2);
    short* bfA     = (short*)alloc((size_t)B_ * H_ * 2);   // h1 -> h3
    short* bfB     = (short*)alloc((size_t)B_ * H_ * 2);   // z  -> t
    short* bfC     = (short*)alloc((size_t)B_ * H_ * 2);   // z_
    float* p_csl   = (float*)alloc(NCSL_BLK * 4);
    float* p_kl    = (float*)alloc(NKL_BLK * 4);
    float* p_rec   = (float*)alloc(NREC_BLK * 4);

    topk_kernel<<<B_, 64, 0, stream>>>(logits, top0, top1, dis);
    gather_d<<<R_, FP_, 0, stream>>>(rels, rel_dict, d_table, dt);

    TransArgs ta;
    auto set = [&](int i, const float* W, short* Wt, int ro, int K, int Kp, int N, int Np, int ilv) {
        ta.W[i] = W; ta.Wt[i] = Wt; ta.row_off[i] = ro; ta.K[i] = K;
        ta.Kpad[i] = Kp; ta.N[i] = N; ta.Npad[i] = Np; ta.ilv[i] = ilv;
    };
    set(0, Wmu, Wt_muls, 0, 512, 512, 512, 512, 0);    // interleaved: rows 64x+[0,32)
    set(1, Wls, Wt_muls, 0, 512, 512, 512, 512, 32);   // interleaved: rows 64x+[32,64)
    set(2, W3,  Wt_3,  0, 512, 512, 512, 512, -1);
    set(3, zW1, Wt_z1, 0, 512, 512, 512, 512, -1);
    set(4, zW2, Wt_z2, 0, 512, 512, 512, 512, -1);
    set(5, W4,  Wt_4,  0, 512, 512, 300, 320, -1);
    set(6, W1,  Wcat_t,              0,  F_, FP_, 512, 512, -1);   // P1
    set(7, W1,  Wcat_t + 512 * FP_,  F_, F_, FP_, 512, 512, -1);   // P2
    set(8, W3,  Wcat_t + 1024 * FP_, L_, F_, FP_, 512, 512, -1);   // P3
    set(9, iW1, Wcat_t + 1536 * FP_, 0,  F_, FP_, 512, 512, -1);   // ipre
    set(10, iW2, Wt_i2, 0, 512, 512, 512, 512, -1);
    transpose_all<<<dim3(16, 16, NT_), 256, 0, stream>>>(ta);

    // Pcat[512][2048] = dt @ Wcat  (no bias)
    gemm_mfma<5, FP_, false><<<dim3(32, 4), 256, 0, stream>>>(
        dt, Wcat_t, Pcat, 2048, nullptr, nullptr, 0, nullptr, nullptr, 2048, nullptr, nullptr, nullptr, nullptr);
    ipre_kernel<<<R_ * H_ / 256, 256, 0, stream>>>(Pcat, ib1, ipre);
    // ipost = relu(ipre @ iW2 + ib2)  fp32
    gemm_mfma<4, 512, false><<<dim3(8, 4), 256, 0, stream>>>(
        ipre, Wt_i2, ipost, 512, ib2, nullptr, 0, nullptr, nullptr, 512, nullptr, nullptr, nullptr, nullptr);

    h1_kernel<<<B_ * H_ / 256, 256, 0, stream>>>(Pcat, b1, top0, top1, bfA);

    dim3 g16(16, 128), g8(8, 128), g5(5, 128);
    // fused mu|ls -> z (bfB), z_ (bfC), kl partials
    gemm_mfma<7, 512, true><<<g16, 256, 0, stream>>>(
        bfA, Wt_muls, bfB, 512, bmu, nullptr, 0, nullptr, p_kl, 1024, bfC, bls, eps1, eps2);
    // h3 = leaky(z @ W3[:512] + Pcat[top1,1024:1536] + b3)
    gemm_mfma<1, 512, true><<<g8, 256, 0, stream>>>(
        bfB, Wt_3, bfA, 512, b3, Pcat + 1024, 2048, top1, nullptr, 512, nullptr, nullptr, nullptr, nullptr);
    gemm_mfma<3, 512, true><<<g5, 256, 0, stream>>>(
        bfA, Wt_4, nullptr, 0, b4, d_table, F_, top0, p_rec, 300, nullptr, nullptr, nullptr, nullptr);
    gemm_mfma<2, 512, true><<<g8, 256, 0, stream>>>(
        bfC, Wt_z1, bfB, 512, zb1, nullptr, 0, nullptr, nullptr, 512, nullptr, nullptr, nullptr, nullptr);
    gemm_mfma<4, 512, true><<<g8, 256, 0, stream>>>(
        bfB, Wt_z2, out + 2 + L_, 512, zb2, nullptr, 0, nullptr, nullptr, 512, nullptr, nullptr, nullptr, nullptr);
    csl_kernel<<<NCSL_BLK, 256, 0, stream>>>(out + 2 + L_, ipost, top0, dis, p_csl);
    finalize_kernel<<<1, 256, 0, stream>>>(p_kl, p_rec, p_csl, out);
}

// Round 7
// 400.531 us; speedup vs baseline: 3.7398x; 1.2040x over previous
//
#include <hip/hip_runtime.h>
#include <math.h>

#define B_ 16384
#define R_ 512
#define V_ 1000
#define F_ 300
#define FP_ 320           // F padded to multiple of 32
#define L_ 512
#define H_ 512
#define LEAK_ 0.2f
#define TEMP_ 0.07f
#define DISK_ 15

#define NCSL_BLK (B_ / 4)      // 4096
#define NKL_BLK  1024          // fused mu|ls gemm128 grid 8x128
#define NREC_BLK (5 * 128)     // 640

typedef short short8 __attribute__((ext_vector_type(8)));
typedef float float4v __attribute__((ext_vector_type(4)));

__device__ __forceinline__ float waveReduceSum(float v) {
#pragma unroll
    for (int off = 32; off; off >>= 1) v += __shfl_xor(v, off);
    return v;
}

__device__ __forceinline__ short f2bf(float f) {
    unsigned u = __float_as_uint(f);
    unsigned r = (u + 0x7FFFu + ((u >> 16) & 1u)) >> 16;
    return (short)r;
}

// async global->LDS, 16B per lane; LDS dest = wave-uniform base + lane*16
__device__ __forceinline__ void gld16(const short* g, short* l) {
    __builtin_amdgcn_global_load_lds(
        (const __attribute__((address_space(1))) void*)g,
        (__attribute__((address_space(3))) void*)l, 16, 0, 0);
}

// ---------------------------------------------------------------------------
// top-2 / bottom-15 per row. one wave per row. (see round-4 notes)
// ---------------------------------------------------------------------------
__global__ __launch_bounds__(64) void topk_kernel(
    const float* __restrict__ logits, int* __restrict__ top0,
    int* __restrict__ top1, int* __restrict__ dis) {
    int b = blockIdx.x;
    int lane = threadIdx.x;
    const float* lp = logits + (size_t)b * R_;
    float4 va = *(const float4*)&lp[lane * 8];
    float4 vb = *(const float4*)&lp[lane * 8 + 4];
    float v[8] = {va.x, va.y, va.z, va.w, vb.x, vb.y, vb.z, vb.w};
    unsigned u[8];
#pragma unroll
    for (int i = 0; i < 8; ++i) {
        int f = __float_as_int(v[i]);
        u[i] = (unsigned)f ^ ((unsigned)(f >> 31) | 0x80000000u);
    }
    unsigned long long t1 = 0ull, t2 = 0ull;
#pragma unroll
    for (int i = 0; i < 8; ++i) {
        unsigned long long k =
            ((unsigned long long)u[i] << 9) | (unsigned)(511 - (lane * 8 + i));
        if (k > t1) { t2 = t1; t1 = k; }
        else if (k > t2) t2 = k;
    }
#pragma unroll
    for (int off = 32; off; off >>= 1) {
        unsigned long long o1 = __shfl_xor(t1, off);
        unsigned long long o2 = __shfl_xor(t2, off);
        unsigned long long hi = t1 > o1 ? t1 : o1;
        unsigned long long lo = t1 > o1 ? o1 : t1;
        unsigned long long m2 = t2 > o2 ? t2 : o2;
        t1 = hi;
        t2 = lo > m2 ? lo : m2;
    }
    int i0 = 511 - (int)(t1 & 511u);
    int i1 = 511 - (int)(t2 & 511u);

    unsigned k32[8];
#pragma unroll
    for (int i = 0; i < 8; ++i) {
        int idx = lane * 8 + i;
        k32[i] = (u[i] & 0xFFFFFE00u) | (unsigned)idx;
        if (idx == i0 || idx == i1) k32[i] = 0xFFFFFFFFu;
    }
    unsigned lmin = k32[0];
#pragma unroll
    for (int i = 1; i < 8; ++i) lmin = min(lmin, k32[i]);
    int dloc[DISK_];
#pragma unroll
    for (int t = 0; t < DISK_; ++t) {
        unsigned w = lmin;
#pragma unroll
        for (int off = 32; off; off >>= 1) w = min(w, __shfl_xor(w, off));
        int idx = (int)(w & 0x1FFu);
        dloc[t] = idx;
        if ((idx >> 3) == lane) {
            k32[idx & 7] = 0xFFFFFFFFu;
            lmin = k32[0];
#pragma unroll
            for (int i = 1; i < 8; ++i) lmin = min(lmin, k32[i]);
        }
    }
    if (lane == 0) {
        top0[b] = i0; top1[b] = i1;
#pragma unroll
        for (int t = 0; t < DISK_; ++t) dis[b * DISK_ + t] = dloc[t];
    }
}

// ---------------------------------------------------------------------------
// gather d_table (fp32) + dt bf16 padded to FP_ cols. one block per relation.
// ---------------------------------------------------------------------------
__global__ __launch_bounds__(FP_) void gather_d(
    const int* __restrict__ rels32, const float* __restrict__ rel_dict,
    float* __restrict__ d_table, short* __restrict__ dt) {
    __shared__ int s_i64;
    int tid = threadIdx.x, r = blockIdx.x;
    if (tid == 0) s_i64 = 1;
    __syncthreads();
    if (rels32[2 * tid + 1] != 0) s_i64 = 0;
    __syncthreads();
    int key = s_i64 ? rels32[4 * r + 2] : rels32[2 * r + 1];
    if (tid < F_) {
        float v = rel_dict[(size_t)key * F_ + tid];
        d_table[(size_t)r * F_ + tid] = v;
        dt[(size_t)r * FP_ + tid] = f2bf(v);
    } else {
        dt[(size_t)r * FP_ + tid] = 0;
    }
}

// ---------------------------------------------------------------------------
// fused transpose of 11 weight views: fp32 W[row_off+K][N] -> bf16 Wt[*][Kpad]
// ilv >= 0: interleaved output row = ilv + 128*(n>>6) + (n&63)  (mu|ls at 64)
// ---------------------------------------------------------------------------
#define NT_ 11
struct TransArgs {
    const float* W[NT_];
    short* Wt[NT_];
    int row_off[NT_];
    int K[NT_];
    int Kpad[NT_];
    int N[NT_];
    int Npad[NT_];
    int ilv[NT_];
};
__global__ __launch_bounds__(256) void transpose_all(TransArgs ta) {
    int z = blockIdx.z;
    const float* W = ta.W[z];
    short* Wt = ta.Wt[z];
    int row_off = ta.row_off[z];
    int K = ta.K[z], Kpad = ta.Kpad[z], N = ta.N[z], Npad = ta.Npad[z];
    int ilv = ta.ilv[z];
    int k0 = blockIdx.x * 32, n0 = blockIdx.y * 32;
    if (k0 >= Kpad || n0 >= Npad) return;
    __shared__ float tile[32][33];
    int tx = threadIdx.x & 31, ty = threadIdx.x >> 5;
#pragma unroll
    for (int i = 0; i < 4; ++i) {
        int k = k0 + i * 8 + ty, n = n0 + tx;
        tile[i * 8 + ty][tx] = (k < K && n < N) ? W[(size_t)(row_off + k) * N + n] : 0.f;
    }
    __syncthreads();
#pragma unroll
    for (int i = 0; i < 4; ++i) {
        int n = n0 + i * 8 + ty, k = k0 + tx;
        if (n < Npad && k < Kpad) {
            int orow = (ilv >= 0) ? (ilv + 128 * (n >> 6) + (n & 63)) : n;
            Wt[(size_t)orow * Kpad + k] = f2bf(tile[tx][i * 8 + ty]);
        }
    }
}

// ---------------------------------------------------------------------------
// h1 = leaky(Pcat[top0,0:512] + Pcat[top1,512:1024] + b1)  -> bf16
// ---------------------------------------------------------------------------
__global__ __launch_bounds__(256) void h1_kernel(
    const float* __restrict__ Pcat, const float* __restrict__ b1,
    const int* __restrict__ top0, const int* __restrict__ top1,
    short* __restrict__ h1b) {
    int idx = blockIdx.x * 256 + threadIdx.x;
    int b = idx >> 9, j = idx & 511;
    float v = Pcat[(size_t)top0[b] * 2048 + j] + Pcat[(size_t)top1[b] * 2048 + 512 + j] + b1[j];
    h1b[idx] = f2bf(v > 0.f ? v : LEAK_ * v);
}

// ---------------------------------------------------------------------------
// ipre = relu(Pcat[:,1536:2048] + ib1) -> bf16
// ---------------------------------------------------------------------------
__global__ __launch_bounds__(256) void ipre_kernel(
    const float* __restrict__ Pcat, const float* __restrict__ ib1,
    short* __restrict__ ipre) {
    int idx = blockIdx.x * 256 + threadIdx.x;   // R_*512 total
    int r = idx >> 9, j = idx & 511;
    float v = Pcat[(size_t)r * 2048 + 1536 + j] + ib1[j];
    ipre[idx] = f2bf(v > 0.f ? v : 0.f);
}

// ---------------------------------------------------------------------------
// m97-style bf16 MFMA GEMM for the B=16384 stages. K=512 fixed.
// Tile 128(M)x128(N), BK=32, 4 waves, global_load_lds (16B) staging,
// 2-barrier K-loop. Wave wv: rows [wv*32, wv*32+32), all 128 cols.
//  EPI 1: bf16 store  leaky(acc + bias + table[rowsel])   (h3)
//  EPI 2: bf16 store  relu(acc + bias)                    (t)
//  EPI 4: fp32 store  relu(acc + bias)                    (z_p -> out)
//  EPI 7: fused mu|ls -> z,z_ bf16 + kl partial. Wt rows [128bx..+64)=mu
//         cols 64bx.., [+64..+128)=ls same cols (ilv=64 interleave).
// ---------------------------------------------------------------------------
template <int EPI>
__global__ __launch_bounds__(256) void gemm128(
    const short* __restrict__ A, const short* __restrict__ Wt,
    void* __restrict__ C, const float* __restrict__ bias,
    const float* __restrict__ table, int tld,
    const int* __restrict__ rowsel, float* __restrict__ lossp,
    void* __restrict__ C2, const float* __restrict__ bias2,
    const float* __restrict__ eps1, const float* __restrict__ eps2) {
    const int K = 512;
    __shared__ __align__(16) short As[128 * 32];
    __shared__ __align__(16) short Bs[128 * 32];
    __shared__ float sred[4];
    int tid = threadIdx.x;
    int lane = tid & 63, wv = tid >> 6;
    int lm = lane & 15, q = lane >> 4;
    int row0 = blockIdx.y * 128, col0 = blockIdx.x * 128;

    // glds addressing: instr covers 16 rows (lane/4) x 32 shorts, lane k-off (lane%4)*8
    int ga0 = row0 + wv * 16 + (lane >> 2);
    int gb0 = col0 + wv * 16 + (lane >> 2);
    int koff = (lane & 3) * 8;
    short* lA0 = As + (wv * 16) * 32;
    short* lA1 = As + (64 + wv * 16) * 32;
    short* lB0 = Bs + (wv * 16) * 32;
    short* lB1 = Bs + (64 + wv * 16) * 32;

    float4v acc[2][8];
#pragma unroll
    for (int i = 0; i < 2; ++i)
#pragma unroll
        for (int j = 0; j < 8; ++j) acc[i][j] = {0.f, 0.f, 0.f, 0.f};

    for (int k0 = 0; k0 < K; k0 += 32) {
        __syncthreads();   // prev iter's LDS reads done before overwrite
        gld16(&A[(size_t)ga0 * K + k0 + koff], lA0);
        gld16(&A[(size_t)(ga0 + 64) * K + k0 + koff], lA1);
        gld16(&Wt[(size_t)gb0 * K + k0 + koff], lB0);
        gld16(&Wt[(size_t)(gb0 + 64) * K + k0 + koff], lB1);
        __syncthreads();   // drains vmcnt -> LDS data visible
        short8 af[2], bf[8];
#pragma unroll
        for (int mt = 0; mt < 2; ++mt)
            af[mt] = *(const short8*)&As[(wv * 32 + mt * 16 + lm) * 32 + q * 8];
#pragma unroll
        for (int nt = 0; nt < 8; ++nt)
            bf[nt] = *(const short8*)&Bs[(nt * 16 + lm) * 32 + q * 8];
#pragma unroll
        for (int mt = 0; mt < 2; ++mt)
#pragma unroll
            for (int nt = 0; nt < 8; ++nt)
                acc[mt][nt] = __builtin_amdgcn_mfma_f32_16x16x32_bf16(
                    af[mt], bf[nt], acc[mt][nt], 0, 0, 0);
    }

    if (EPI == 7) {
        float kl = 0.f;
#pragma unroll
        for (int mt = 0; mt < 2; ++mt) {
#pragma unroll
            for (int r = 0; r < 4; ++r) {
                int grow = row0 + wv * 32 + mt * 16 + q * 4 + r;
#pragma unroll
                for (int jj = 0; jj < 4; ++jj) {
                    int j = (col0 >> 1) + jj * 16 + lm;
                    float m = acc[mt][jj][r] + bias[j];
                    float lsv = acc[mt][jj + 4][r] + bias2[j];
                    float s = __expf(lsv);
                    size_t ix = (size_t)grow * 512 + j;
                    ((short*)C)[ix]  = f2bf(m + eps1[ix] * s);
                    ((short*)C2)[ix] = f2bf(m + eps2[ix] * s);
                    kl += -0.5f * (1.f + 2.f * lsv - m * m - s * s);
                }
            }
        }
        kl = waveReduceSum(kl);
        if (lane == 0) sred[wv] = kl;
        __syncthreads();
        if (tid == 0)
            lossp[blockIdx.x + gridDim.x * blockIdx.y] =
                sred[0] + sred[1] + sred[2] + sred[3];
    } else {
#pragma unroll
        for (int mt = 0; mt < 2; ++mt) {
#pragma unroll
            for (int r = 0; r < 4; ++r) {
                int grow = row0 + wv * 32 + mt * 16 + q * 4 + r;
                int trow = (EPI == 1) ? rowsel[grow] : 0;
#pragma unroll
                for (int nt = 0; nt < 8; ++nt) {
                    int gcol = col0 + nt * 16 + lm;
                    float v = acc[mt][nt][r] + bias[gcol];
                    if (EPI == 1) {
                        v += table[(size_t)trow * tld + gcol];
                        v = v > 0.f ? v : LEAK_ * v;
                    }
                    if (EPI == 2 || EPI == 4) v = v > 0.f ? v : 0.f;
                    if (EPI == 4)
                        ((float*)C)[(size_t)grow * 512 + gcol] = v;
                    else
                        ((short*)C)[(size_t)grow * 512 + gcol] = f2bf(v);
                }
            }
        }
    }
}

// ---------------------------------------------------------------------------
// small-M bf16 MFMA GEMM (R=512 tables): tile 128x64, BK=32, dbuf LDS.
//  EPI 3: partial[l] = sum (tanh(acc+bias)-table[rowsel])^2   (recon, B=16384)
//  EPI 4: fp32 store  relu(acc + bias)                        (ipost)
//  EPI 5: fp32 store  acc (no bias)                           (Pcat)
// ---------------------------------------------------------------------------
template <int EPI, int KK>
__global__ __launch_bounds__(256) void gemm_mfma(
    const short* __restrict__ A, const short* __restrict__ Wt,
    void* __restrict__ C, int ldc, const float* __restrict__ bias,
    const float* __restrict__ table, int tld,
    const int* __restrict__ rowsel, float* __restrict__ lossp, int N) {
    __shared__ __align__(16) short Asl[2][128][40];
    __shared__ __align__(16) short Bsl[2][64][40];
    __shared__ float sred[4];
    int tid = threadIdx.x;
    int lane = tid & 63, wv = tid >> 6;
    int lm = lane & 15, q = lane >> 4;
    int row0 = blockIdx.y * 128;
    int col0 = blockIdx.x * 64;

    float4v acc[2][4];
#pragma unroll
    for (int i = 0; i < 2; ++i)
#pragma unroll
        for (int j = 0; j < 4; ++j) acc[i][j] = {0.f, 0.f, 0.f, 0.f};

    uint4 aReg[2], bReg;
    int ar0 = tid >> 2, ak = (tid & 3) * 8;
    int ar1 = (tid + 256) >> 2;
    int br = tid >> 2, bk = (tid & 3) * 8;

    auto loadG = [&](int k0) {
        aReg[0] = *(const uint4*)&A[(size_t)(row0 + ar0) * KK + k0 + ak];
        aReg[1] = *(const uint4*)&A[(size_t)(row0 + ar1) * KK + k0 + ak];
        bReg    = *(const uint4*)&Wt[(size_t)(col0 + br) * KK + k0 + bk];
    };
    auto storeL = [&](int p) {
        *(uint4*)&Asl[p][ar0][ak] = aReg[0];
        *(uint4*)&Asl[p][ar1][ak] = aReg[1];
        *(uint4*)&Bsl[p][br][bk]  = bReg;
    };

    int p = 0;
    loadG(0);
    storeL(0);
    for (int k0 = 0; k0 < KK; k0 += 32) {
        __syncthreads();
        bool more = (k0 + 32) < KK;
        if (more) loadG(k0 + 32);
        short8 af[2], bfr[4];
#pragma unroll
        for (int mt = 0; mt < 2; ++mt)
            af[mt] = *(const short8*)&Asl[p][wv * 32 + mt * 16 + lm][q * 8];
#pragma unroll
        for (int nt = 0; nt < 4; ++nt)
            bfr[nt] = *(const short8*)&Bsl[p][nt * 16 + lm][q * 8];
#pragma unroll
        for (int mt = 0; mt < 2; ++mt)
#pragma unroll
            for (int nt = 0; nt < 4; ++nt)
                acc[mt][nt] = __builtin_amdgcn_mfma_f32_16x16x32_bf16(
                    af[mt], bfr[nt], acc[mt][nt], 0, 0, 0);
        if (more) { p ^= 1; storeL(p); }
    }

    if (EPI == 3) {
        float lsum = 0.f;
#pragma unroll
        for (int mt = 0; mt < 2; ++mt) {
#pragma unroll
            for (int r = 0; r < 4; ++r) {
                int grow = row0 + wv * 32 + mt * 16 + q * 4 + r;
                int trow = rowsel[grow];
#pragma unroll
                for (int nt = 0; nt < 4; ++nt) {
                    int gcol = col0 + nt * 16 + lm;
                    if (gcol < N) {
                        float v = tanhf(acc[mt][nt][r] + bias[gcol]);
                        float d = v - table[(size_t)trow * tld + gcol];
                        lsum += d * d;
                    }
                }
            }
        }
        lsum = waveReduceSum(lsum);
        if (lane == 0) sred[wv] = lsum;
        __syncthreads();
        if (tid == 0)
            lossp[blockIdx.x + gridDim.x * blockIdx.y] =
                sred[0] + sred[1] + sred[2] + sred[3];
    } else {
#pragma unroll
        for (int mt = 0; mt < 2; ++mt) {
#pragma unroll
            for (int r = 0; r < 4; ++r) {
                int grow = row0 + wv * 32 + mt * 16 + q * 4 + r;
#pragma unroll
                for (int nt = 0; nt < 4; ++nt) {
                    int gcol = col0 + nt * 16 + lm;
                    float v = acc[mt][nt][r];
                    if (EPI == 4) { v += bias[gcol]; v = v > 0.f ? v : 0.f; }
                    ((float*)C)[(size_t)grow * ldc + gcol] = v;
                }
            }
        }
    }
}

// ---------------------------------------------------------------------------
// contrastive loss: one wave per row, per-block partial (no atomics)
// ---------------------------------------------------------------------------
__global__ __launch_bounds__(256) void csl_kernel(
    const float* __restrict__ zp, const float* __restrict__ ipost,
    const int* __restrict__ top0, const int* __restrict__ dis,
    float* __restrict__ partial_csl) {
    __shared__ float sred[4];
    int w = threadIdx.x >> 6, lane = threadIdx.x & 63;
    int b = blockIdx.x * 4 + w;
    const float* zr = zp + (size_t)b * 512;
    float z[8];
#pragma unroll
    for (int i = 0; i < 8; ++i) z[i] = zr[i * 64 + lane];
    int cand[16];
    cand[0] = top0[b];
#pragma unroll
    for (int n = 0; n < DISK_; ++n) cand[n + 1] = dis[b * DISK_ + n];
    float s[16];
#pragma unroll
    for (int c = 0; c < 16; ++c) {
        const float* ip = ipost + (size_t)cand[c] * 512;
        float a = 0.f;
#pragma unroll
        for (int i = 0; i < 8; ++i) a += z[i] * ip[i * 64 + lane];
        s[c] = a;
    }
#pragma unroll
    for (int off = 32; off; off >>= 1) {
        float o[16];
#pragma unroll
        for (int c = 0; c < 16; ++c) o[c] = __shfl_xor(s[c], off);
#pragma unroll
        for (int c = 0; c < 16; ++c) s[c] += o[c];
    }
    if (lane == 0) {
        float m = s[0];
#pragma unroll
        for (int c = 1; c < 16; ++c) m = fmaxf(m, s[c]);
        float se = 0.f;
#pragma unroll
        for (int c = 0; c < 16; ++c) se += __expf((s[c] - m) / TEMP_);
        sred[w] = -((s[0] - m) / TEMP_ - __logf(se));
    }
    __syncthreads();
    if (threadIdx.x == 0)
        partial_csl[blockIdx.x] = sred[0] + sred[1] + sred[2] + sred[3];
}

// ---------------------------------------------------------------------------
// finalize: out[0] = kl + recon; out[1] = csl; out[2..513] = 0 (z_rel row 0)
// ---------------------------------------------------------------------------
__global__ __launch_bounds__(256) void finalize_kernel(
    const float* __restrict__ pkl, const float* __restrict__ prec,
    const float* __restrict__ pcsl, float* __restrict__ out) {
    __shared__ float red[4][2];
    int tid = threadIdx.x;
    out[2 + tid] = 0.f;
    out[2 + 256 + tid] = 0.f;
    float a0 = 0.f, a1 = 0.f;
    for (int i = tid; i < NKL_BLK; i += 256) a0 += pkl[i];
    for (int i = tid; i < NREC_BLK; i += 256) a0 += prec[i];
    for (int i = tid; i < NCSL_BLK; i += 256) a1 += pcsl[i];
    a0 = waveReduceSum(a0);
    a1 = waveReduceSum(a1);
    int lane = tid & 63, w = tid >> 6;
    if (lane == 0) { red[w][0] = a0; red[w][1] = a1; }
    __syncthreads();
    if (tid == 0) out[0] = red[0][0] + red[1][0] + red[2][0] + red[3][0];
    if (tid == 1) out[1] = red[0][1] + red[1][1] + red[2][1] + red[3][1];
}

// ---------------------------------------------------------------------------
extern "C" void kernel_launch(void* const* d_in, const int* in_sizes, int n_in,
                              void* d_out, int out_size, void* d_ws, size_t ws_size,
                              hipStream_t stream) {
    const float* logits  = (const float*)d_in[0];
    const int*   rels    = (const int*)d_in[1];
    const float* rel_dict= (const float*)d_in[2];
    const float* eps1    = (const float*)d_in[3];
    const float* eps2    = (const float*)d_in[4];
    const float* W1  = (const float*)d_in[5];
    const float* b1  = (const float*)d_in[6];
    const float* Wmu = (const float*)d_in[7];
    const float* bmu = (const float*)d_in[8];
    const float* Wls = (const float*)d_in[9];
    const float* bls = (const float*)d_in[10];
    const float* W3  = (const float*)d_in[11];
    const float* b3  = (const float*)d_in[12];
    const float* W4  = (const float*)d_in[13];
    const float* b4  = (const float*)d_in[14];
    const float* iW1 = (const float*)d_in[15];
    const float* ib1 = (const float*)d_in[16];
    const float* iW2 = (const float*)d_in[17];
    const float* ib2 = (const float*)d_in[18];
    const float* zW1 = (const float*)d_in[19];
    const float* zb1 = (const float*)d_in[20];
    const float* zW2 = (const float*)d_in[21];
    const float* zb2 = (const float*)d_in[22];
    float* out = (float*)d_out;

    char* wsp = (char*)d_ws;
    size_t off = 0;
    auto alloc = [&](size_t bytes) { void* p = wsp + off; off += (bytes + 255) & ~(size_t)255; return p; };
    int*   top0    = (int*)alloc(B_ * 4);
    int*   top1    = (int*)alloc(B_ * 4);
    int*   dis     = (int*)alloc(B_ * DISK_ * 4);
    float* d_table = (float*)alloc((size_t)R_ * F_ * 4);
    short* dt      = (short*)alloc((size_t)R_ * FP_ * 2);
    short* Wcat_t  = (short*)alloc((size_t)2048 * FP_ * 2);
    float* Pcat    = (float*)alloc((size_t)R_ * 2048 * 4);
    short* ipre    = (short*)alloc((size_t)R_ * H_ * 2);
    float* ipost   = (float*)alloc((size_t)R_ * H_ * 4);
    short* Wt_muls = (short*)alloc((size_t)1024 * 512 * 2);
    short* Wt_3    = (short*)alloc((size_t)512 * 512 * 2);
    short* Wt_z1   = (short*)alloc((size_t)512 * 512 * 2);
    short* Wt_z2   = (short*)alloc((size_t)512 * 512 * 2);
    short* Wt_4    = (short*)alloc((size_t)320 * 512 * 2);
    short* Wt_i2   = (short*)alloc((size_t)512 * 512 * 2);
    short* bfA     = (short*)alloc((size_t)B_ * H_ * 2);   // h1 -> h3
    short* bfB     = (short*)alloc((size_t)B_ * H_ * 2);   // z  -> t
    short* bfC     = (short*)alloc((size_t)B_ * H_ * 2);   // z_
    float* p_csl   = (float*)alloc(NCSL_BLK * 4);
    float* p_kl    = (float*)alloc(NKL_BLK * 4);
    float* p_rec   = (float*)alloc(NREC_BLK * 4);

    topk_kernel<<<B_, 64, 0, stream>>>(logits, top0, top1, dis);
    gather_d<<<R_, FP_, 0, stream>>>(rels, rel_dict, d_table, dt);

    TransArgs ta;
    auto set = [&](int i, const float* W, short* Wt, int ro, int K, int Kp, int N, int Np, int ilv) {
        ta.W[i] = W; ta.Wt[i] = Wt; ta.row_off[i] = ro; ta.K[i] = K;
        ta.Kpad[i] = Kp; ta.N[i] = N; ta.Npad[i] = Np; ta.ilv[i] = ilv;
    };
    set(0, Wmu, Wt_muls, 0, 512, 512, 512, 512, 0);    // rows 128c+[0,64)
    set(1, Wls, Wt_muls, 0, 512, 512, 512, 512, 64);   // rows 128c+[64,128)
    set(2, W3,  Wt_3,  0, 512, 512, 512, 512, -1);
    set(3, zW1, Wt_z1, 0, 512, 512, 512, 512, -1);
    set(4, zW2, Wt_z2, 0, 512, 512, 512, 512, -1);
    set(5, W4,  Wt_4,  0, 512, 512, 300, 320, -1);
    set(6, W1,  Wcat_t,              0,  F_, FP_, 512, 512, -1);   // P1
    set(7, W1,  Wcat_t + 512 * FP_,  F_, F_, FP_, 512, 512, -1);   // P2
    set(8, W3,  Wcat_t + 1024 * FP_, L_, F_, FP_, 512, 512, -1);   // P3
    set(9, iW1, Wcat_t + 1536 * FP_, 0,  F_, FP_, 512, 512, -1);   // ipre
    set(10, iW2, Wt_i2, 0, 512, 512, 512, 512, -1);
    transpose_all<<<dim3(16, 16, NT_), 256, 0, stream>>>(ta);

    // Pcat[512][2048] = dt @ Wcat  (no bias)
    gemm_mfma<5, FP_><<<dim3(32, 4), 256, 0, stream>>>(
        dt, Wcat_t, Pcat, 2048, nullptr, nullptr, 0, nullptr, nullptr, 2048);
    ipre_kernel<<<R_ * H_ / 256, 256, 0, stream>>>(Pcat, ib1, ipre);
    // ipost = relu(ipre @ iW2 + ib2)  fp32
    gemm_mfma<4, 512><<<dim3(8, 4), 256, 0, stream>>>(
        ipre, Wt_i2, ipost, 512, ib2, nullptr, 0, nullptr, nullptr, 512);

    h1_kernel<<<B_ * H_ / 256, 256, 0, stream>>>(Pcat, b1, top0, top1, bfA);

    dim3 g8(8, 128), g4(4, 128), g5(5, 128);
    // fused mu|ls -> z (bfB), z_ (bfC), kl partials
    gemm128<7><<<g8, 256, 0, stream>>>(
        bfA, Wt_muls, bfB, bmu, nullptr, 0, nullptr, p_kl, bfC, bls, eps1, eps2);
    // h3 = leaky(z @ W3[:512] + Pcat[top1,1024:1536] + b3)
    gemm128<1><<<g4, 256, 0, stream>>>(
        bfB, Wt_3, bfA, b3, Pcat + 1024, 2048, top1, nullptr, nullptr, nullptr, nullptr, nullptr);
    // recon loss
    gemm_mfma<3, 512><<<g5, 256, 0, stream>>>(
        bfA, Wt_4, nullptr, 0, b4, d_table, F_, top0, p_rec, 300);
    // t = relu(z_ @ zW1 + zb1)
    gemm128<2><<<g4, 256, 0, stream>>>(
        bfC, Wt_z1, bfB, zb1, nullptr, 0, nullptr, nullptr, nullptr, nullptr, nullptr, nullptr);
    // z_p = relu(t @ zW2 + zb2) -> z_rel rows 1..B
    gemm128<4><<<g4, 256, 0, stream>>>(
        bfB, Wt_z2, out + 2 + L_, zb2, nullptr, 0, nullptr, nullptr, nullptr, nullptr, nullptr, nullptr);
    csl_kernel<<<NCSL_BLK, 256, 0, stream>>>(out + 2 + L_, ipost, top0, dis, p_csl);
    finalize_kernel<<<1, 256, 0, stream>>>(p_kl, p_rec, p_csl, out);
}